// Round 8
// baseline (5050.607 us; speedup 1.0000x reference)
//
#include <hip/hip_runtime.h>

#define NV   50000
#define FD   128
#define NE   800000
#define NOUT 64
#define NBIN 196           // src buckets of 256 nodes
#define NBIN2 782          // dst buckets of 64 nodes: ceil(NV/64)
#define CH   2048          // edges per block in bucket passes
#define NBLK 391           // ceil(NE/CH)
#define SCAN_L  (NBIN * NBLK)     // 76,636
#define SCAN_L2 (NBIN2 * NBLK)    // 305,762
#define SCHUNK 2048
#define NSCH  ((SCAN_L  + SCHUNK - 1) / SCHUNK)   // 38
#define NSCH2 ((SCAN_L2 + SCHUNK - 1) / SCHUNK)   // 150

typedef unsigned short bf16_t;
typedef unsigned char  u8;
typedef unsigned short u16;
typedef __attribute__((ext_vector_type(8))) short bf16x8;
typedef __attribute__((ext_vector_type(4))) float f32x4;

__device__ __forceinline__ bf16_t f2bf(float f) {
  unsigned u = __builtin_bit_cast(unsigned, f);
  return (bf16_t)((u + 0x7fffu + ((u >> 16) & 1u)) >> 16);
}
__device__ __forceinline__ float bflo(unsigned v) { return __builtin_bit_cast(float, v << 16); }
__device__ __forceinline__ float bfhi(unsigned v) { return __builtin_bit_cast(float, v & 0xffff0000u); }
__device__ __forceinline__ unsigned pk2(float a, float b) {
  return (unsigned)f2bf(a) | ((unsigned)f2bf(b) << 16);
}

struct Ptr4 { const int* p[4]; };

// ================= stage 1: bucket edges by src>>8 =================

__global__ __launch_bounds__(256) void p0s_hist(Ptr4 rows, int* __restrict__ blockCnt) {
  const int r = blockIdx.y, blk = blockIdx.x, t = threadIdx.x;
  __shared__ int cs[NBIN];
  for (int i = t; i < NBIN; i += 256) cs[i] = 0;
  __syncthreads();
  const int e0 = blk * CH;
  const int n = min(CH, NE - e0);
  const int* rw = rows.p[r] + e0;
  for (int i = t; i < n; i += 256) atomicAdd(&cs[rw[i] >> 8], 1);
  __syncthreads();
  int* b = blockCnt + (size_t)r * SCAN_L;
  for (int i = t; i < NBIN; i += 256) b[i * NBLK + blk] = cs[i];
}

// ---- hierarchical exclusive scan (templated; used for both stages) ----
template<int LEN, int NCH>
__global__ __launch_bounds__(256) void t_pass1(const int* __restrict__ bc,
                                               int* __restrict__ csum) {
  const int win = blockIdx.y, chunk = blockIdx.x, t = threadIdx.x;
  const int* a = bc + (size_t)win * LEN + chunk * SCHUNK;
  const int n = min(SCHUNK, LEN - chunk * SCHUNK);
  int s = 0;
  for (int i = t; i < n; i += 256) s += a[i];
  __shared__ int sm[256];
  sm[t] = s;
  __syncthreads();
  #pragma unroll
  for (int off = 128; off > 0; off >>= 1) {
    if (t < off) sm[t] += sm[t + off];
    __syncthreads();
  }
  if (t == 0) csum[win * NCH + chunk] = sm[0];
}

template<int NWIN, int NCH, int NBINX>
__global__ __launch_bounds__(1024) void t_pass2(int* __restrict__ csum,
                                                int* __restrict__ bb) {
  const int t = threadIdx.x;
  __shared__ int sm[NWIN * NCH];
  if (t < NWIN * NCH) sm[t] = csum[t];
  __syncthreads();
  if (t < NWIN) {
    int run = 0;
    for (int j = 0; j < NCH; ++j) { int v = sm[t * NCH + j]; sm[t * NCH + j] = run; run += v; }
    bb[t * (NBINX + 1) + NBINX] = NE;
  }
  __syncthreads();
  if (t < NWIN * NCH) csum[t] = sm[t];
}

template<int LEN, int NCH, int NBINX>
__global__ __launch_bounds__(256) void t_pass3(int* __restrict__ bc,
                                               const int* __restrict__ csum,
                                               int* __restrict__ bb) {
  const int win = blockIdx.y, chunk = blockIdx.x, t = threadIdx.x;
  int* a = bc + (size_t)win * LEN + chunk * SCHUNK;
  const int gbase = chunk * SCHUNK;
  const int n = min(SCHUNK, LEN - gbase);
  const int idx0 = t * 8;
  int v[8];
  int s = 0;
  #pragma unroll
  for (int j = 0; j < 8; ++j) {
    int id = idx0 + j;
    v[j] = (id < n) ? a[id] : 0;
    s += v[j];
  }
  __shared__ int sm[256];
  sm[t] = s;
  __syncthreads();
  for (int off = 1; off < 256; off <<= 1) {
    int x = (t >= off) ? sm[t - off] : 0;
    __syncthreads();
    sm[t] += x;
    __syncthreads();
  }
  int pre = ((t == 0) ? 0 : sm[t - 1]) + csum[win * NCH + chunk];
  #pragma unroll
  for (int j = 0; j < 8; ++j) {
    int id = idx0 + j;
    if (id < n) {
      int val = v[j];
      a[id] = pre;
      int g = gbase + id;
      if (g % NBLK == 0) bb[win * (NBINX + 1) + g / NBLK] = pre;
      pre += val;
    }
  }
}

// stage-1 scatter: edges -> pairS[(dst<<16)|src], src-bucket-major (stable per chunk)
__global__ __launch_bounds__(256) void p1s_scatter(Ptr4 rows, Ptr4 cols,
                                                   const int* __restrict__ blockCnt,
                                                   unsigned* __restrict__ pairS) {
  const int r = blockIdx.y, blk = blockIdx.x, t = threadIdx.x;
  const int e0 = blk * CH;
  const int n = min(CH, NE - e0);
  const int* rw = rows.p[r] + e0;
  const int* cl = cols.p[r] + e0;

  __shared__ int cnt[256], sc[256], lofs[256], cnt2[256], baseT[256];
  __shared__ unsigned pr[CH];
  __shared__ u8 binb[CH];
  cnt[t] = 0; cnt2[t] = 0;
  __syncthreads();
  for (int i = t; i < n; i += 256) atomicAdd(&cnt[rw[i] >> 8], 1);
  __syncthreads();
  sc[t] = cnt[t];
  __syncthreads();
  for (int off = 1; off < 256; off <<= 1) {
    int v = (t >= off) ? sc[t - off] : 0;
    __syncthreads();
    sc[t] += v;
    __syncthreads();
  }
  lofs[t] = (t == 0) ? 0 : sc[t - 1];
  if (t < NBIN) baseT[t] = blockCnt[(size_t)r * SCAN_L + t * NBLK + blk];
  __syncthreads();
  for (int i = t; i < n; i += 256) {
    int sv = rw[i];
    int bin = sv >> 8;
    int rank = atomicAdd(&cnt2[bin], 1);
    int p = lofs[bin] + rank;
    pr[p] = ((unsigned)cl[i] << 16) | (unsigned)sv;
    binb[p] = (u8)bin;
  }
  __syncthreads();
  unsigned* ps = pairS + (size_t)r * NE;
  for (int i = t; i < n; i += 256) {
    int bin = binb[i];
    ps[baseT[bin] + (i - lofs[bin])] = pr[i];
  }
}

// src degrees -> dinvS
__global__ __launch_bounds__(256) void p2_srcdeg(const unsigned* __restrict__ pairS,
                                                 const int* __restrict__ srcBase,
                                                 float* __restrict__ dinvS) {
  const int r = blockIdx.y, bin = blockIdx.x, t = threadIdx.x;
  const int base = srcBase[r * (NBIN + 1) + bin];
  const int next = srcBase[r * (NBIN + 1) + bin + 1];
  const int span = next - base;
  const unsigned* ps = pairS + (size_t)r * NE + base;
  __shared__ int cnt[256];
  cnt[t] = 0;
  __syncthreads();
  for (int i = t; i < span; i += 256) atomicAdd(&cnt[ps[i] & 255], 1);
  __syncthreads();
  int node = (bin << 8) + t;
  if (node < NV) {
    float deg = (float)cnt[t];
    dinvS[r * NV + node] = (r < 2) ? rsqrtf(deg + 1.f)
                                   : (deg > 0.f ? rsqrtf(deg) : 0.f);
  }
}

// ================= stage 2: bucket src-sorted stream by dst>>6 =================

__global__ __launch_bounds__(256) void p0d2(const unsigned* __restrict__ pairS,
                                            int* __restrict__ blockCnt2) {
  const int r = blockIdx.y, blk = blockIdx.x, t = threadIdx.x;
  __shared__ int cd[NBIN2];
  for (int i = t; i < NBIN2; i += 256) cd[i] = 0;
  __syncthreads();
  const int e0 = blk * CH;
  const int n = min(CH, NE - e0);
  const unsigned* pp = pairS + (size_t)r * NE + e0;
  for (int i = t; i < n; i += 256) atomicAdd(&cd[(pp[i] >> 16) >> 6], 1);
  __syncthreads();
  int* b = blockCnt2 + (size_t)r * SCAN_L2;
  for (int i = t; i < NBIN2; i += 256) b[i * NBLK + blk] = cd[i];
}

// stage-2 scatter: pairS -> edge2[(dst_local<<16)|src], dst-bucket-major,
// preserving src-sorted stream order segment-wise
__global__ __launch_bounds__(256) void p1d2(const unsigned* __restrict__ pairS,
                                            const int* __restrict__ blockCnt2,
                                            unsigned* __restrict__ edge2) {
  const int r = blockIdx.y, blk = blockIdx.x, t = threadIdx.x;
  const int e0 = blk * CH;
  const int n = min(CH, NE - e0);
  const unsigned* pp = pairS + (size_t)r * NE + e0;

  __shared__ int cnt[NBIN2], lofs[NBIN2], cnt2[NBIN2], baseT[NBIN2], sc[256];
  __shared__ unsigned pr[CH];
  __shared__ u16 binb[CH];
  for (int i = t; i < NBIN2; i += 256) { cnt[i] = 0; cnt2[i] = 0; }
  __syncthreads();
  for (int i = t; i < n; i += 256) atomicAdd(&cnt[(pp[i] >> 16) >> 6], 1);
  __syncthreads();
  const int b0 = t * 4;
  int part = 0;
  #pragma unroll
  for (int j = 0; j < 4; ++j) if (b0 + j < NBIN2) part += cnt[b0 + j];
  sc[t] = part;
  __syncthreads();
  for (int off = 1; off < 256; off <<= 1) {
    int v = (t >= off) ? sc[t - off] : 0;
    __syncthreads();
    sc[t] += v;
    __syncthreads();
  }
  int run = (t == 0) ? 0 : sc[t - 1];
  #pragma unroll
  for (int j = 0; j < 4; ++j)
    if (b0 + j < NBIN2) { lofs[b0 + j] = run; run += cnt[b0 + j]; }
  for (int i = t; i < NBIN2; i += 256)
    baseT[i] = blockCnt2[(size_t)r * SCAN_L2 + i * NBLK + blk];
  __syncthreads();
  for (int i = t; i < n; i += 256) {
    unsigned v = pp[i];
    int dst = v >> 16;
    int bin = dst >> 6;
    int rank = atomicAdd(&cnt2[bin], 1);
    int p = lofs[bin] + rank;
    pr[p] = ((unsigned)(dst & 63) << 16) | (v & 0xFFFFu);
    binb[p] = (u16)bin;
  }
  __syncthreads();
  unsigned* eo = edge2 + (size_t)r * NE;
  for (int i = t; i < n; i += 256) {
    int bin = binb[i];
    eo[baseT[bin] + (i - lofs[bin])] = pr[i];
  }
}

// ================= dtype prep =================

__global__ __launch_bounds__(256) void xcvt(const float* __restrict__ x,
                                            bf16_t* __restrict__ xb, int n4) {
  int i = blockIdx.x * 256 + threadIdx.x;
  if (i < n4) {
    float4 v = *(const float4*)(x + (size_t)i * 4);
    *(uint2*)(xb + (size_t)i * 4) = make_uint2(pk2(v.x, v.y), pk2(v.z, v.w));
  }
}

// W[8][128k][128n] fp32 -> Wt[8][128n][128k] bf16 (transposed)
__global__ __launch_bounds__(256) void wprep(const float* __restrict__ Wsrc,
                                             bf16_t* __restrict__ Wt) {
  int idx = blockIdx.x * 256 + threadIdx.x;
  if (idx < 8 * 128 * 128) {
    int i = idx >> 14, n = (idx >> 7) & 127, k = idx & 127;
    Wt[idx] = f2bf(Wsrc[(size_t)i * 16384 + k * 128 + n]);
  }
}

// ================= pull: LDS-accumulated push within 64-node dst bucket =========
// agg_r[i] = sum_{edges s->i in r} dS_r[s] * x_s  (+ dS_r[i]*x_i if homog)
// Also emits dD_r[i] = rsqrt(deg + self) (0 if empty, hetero).
__global__ __launch_bounds__(512) void pull_push(
    const bf16_t* __restrict__ xd, const bf16_t* __restrict__ xs,
    const unsigned* __restrict__ edge2, const int* __restrict__ bb2,
    const float* __restrict__ dinvS,
    bf16_t* __restrict__ agg, float* __restrict__ dDall) {
  const int type = blockIdx.y;            // 0: drug dst, 1: dis dst
  const int bkt = blockIdx.x;
  const int rA = type == 0 ? 0 : 1;       // homogeneous relation
  const int rB = type == 0 ? 3 : 2;       // cross relation
  const bf16_t* tabA = type == 0 ? xd : xs;
  const bf16_t* tabB = type == 0 ? xs : xd;
  const int node0 = bkt * 64;

  __shared__ float accF[64][132];         // +4 pad: spreads rows across banks
  __shared__ int degL[64];
  const int t = threadIdx.x;
  const int wave = t >> 6, lane = t & 63;

  #pragma unroll
  for (int phase = 0; phase < 2; ++phase) {
    const int r = phase ? rB : rA;
    const bf16_t* tab = phase ? tabB : tabA;
    const float* dS = dinvS + r * NV;
    // zero accumulators
    for (int i = t; i < 64 * 132 / 4; i += 512) ((float4*)accF)[i] = make_float4(0, 0, 0, 0);
    if (t < 64) degL[t] = 0;
    __syncthreads();

    const unsigned* seg = edge2 + (size_t)r * NE;
    const int e1 = bb2[r * (NBIN2 + 1) + bkt + 1];
    int j = bb2[r * (NBIN2 + 1) + bkt] + wave * 4;
    // 4 edges in flight per wave; consecutive edges per wave for sweep locality
    for (; j + 4 <= e1; j += 32) {
      unsigned ev0 = seg[j], ev1 = seg[j + 1], ev2 = seg[j + 2], ev3 = seg[j + 3];
      int s0 = ev0 & 0xFFFF, s1 = ev1 & 0xFFFF, s2 = ev2 & 0xFFFF, s3 = ev3 & 0xFFFF;
      float w0 = dS[s0], w1 = dS[s1], w2 = dS[s2], w3 = dS[s3];
      unsigned x0 = *(const unsigned*)(tab + ((size_t)s0 << 7) + lane * 2);
      unsigned x1 = *(const unsigned*)(tab + ((size_t)s1 << 7) + lane * 2);
      unsigned x2 = *(const unsigned*)(tab + ((size_t)s2 << 7) + lane * 2);
      unsigned x3 = *(const unsigned*)(tab + ((size_t)s3 << 7) + lane * 2);
      int d0 = ev0 >> 16, d1 = ev1 >> 16, d2 = ev2 >> 16, d3 = ev3 >> 16;
      atomicAdd(&accF[d0][lane * 2], w0 * bflo(x0));
      atomicAdd(&accF[d0][lane * 2 + 1], w0 * bfhi(x0));
      atomicAdd(&accF[d1][lane * 2], w1 * bflo(x1));
      atomicAdd(&accF[d1][lane * 2 + 1], w1 * bfhi(x1));
      atomicAdd(&accF[d2][lane * 2], w2 * bflo(x2));
      atomicAdd(&accF[d2][lane * 2 + 1], w2 * bfhi(x2));
      atomicAdd(&accF[d3][lane * 2], w3 * bflo(x3));
      atomicAdd(&accF[d3][lane * 2 + 1], w3 * bfhi(x3));
      if (lane == 0) {
        atomicAdd(&degL[d0], 1); atomicAdd(&degL[d1], 1);
        atomicAdd(&degL[d2], 1); atomicAdd(&degL[d3], 1);
      }
    }
    for (; j < e1; ++j) {
      unsigned ev = seg[j];
      int s = ev & 0xFFFF, dl = ev >> 16;
      float w = dS[s];
      unsigned xv = *(const unsigned*)(tab + ((size_t)s << 7) + lane * 2);
      atomicAdd(&accF[dl][lane * 2], w * bflo(xv));
      atomicAdd(&accF[dl][lane * 2 + 1], w * bfhi(xv));
      if (lane == 0) atomicAdd(&degL[dl], 1);
    }
    // self loop for homogeneous relation
    if (phase == 0) {
      for (int nloc = wave; nloc < 64; nloc += 8) {
        int node = node0 + nloc;
        if (node < NV) {
          float w = dS[node];
          unsigned xv = *(const unsigned*)(tabA + ((size_t)node << 7) + lane * 2);
          atomicAdd(&accF[nloc][lane * 2], w * bflo(xv));
          atomicAdd(&accF[nloc][lane * 2 + 1], w * bfhi(xv));
        }
      }
    }
    __syncthreads();
    // write agg (bf16) and dD
    {
      bf16_t* aggR = agg + (size_t)r * NV * FD;
      int dl = t >> 3, q = t & 7;                       // 64 rows x 8 segs of 16 dims
      int node = node0 + dl;
      if (node < NV) {
        const float* src = &accF[dl][q * 16];
        uint4 o0, o1;
        o0.x = pk2(src[0], src[1]);   o0.y = pk2(src[2], src[3]);
        o0.z = pk2(src[4], src[5]);   o0.w = pk2(src[6], src[7]);
        o1.x = pk2(src[8], src[9]);   o1.y = pk2(src[10], src[11]);
        o1.z = pk2(src[12], src[13]); o1.w = pk2(src[14], src[15]);
        uint4* dst = (uint4*)(aggR + (size_t)node * FD + q * 16);
        dst[0] = o0; dst[1] = o1;
      }
      if (t < 64) {
        int nd = node0 + t;
        if (nd < NV) {
          float dg = (float)(degL[t] + ((r < 2) ? 1 : 0));
          dDall[r * NV + nd] = dg > 0.f ? rsqrtf(dg) : 0.f;
        }
      }
    }
    __syncthreads();
  }
}

// ================= pair GEMM: Y = relu(dD0*(A0@W0) + dD1*(A1@W1) + b0 + b1) =====
struct GP {
  const bf16_t* A0; const float* dD0; const bf16_t* W0;
  const bf16_t* A1; const float* dD1; const bf16_t* W1;
  const float* b0; const float* b1; bf16_t* Y;
};

__global__ __launch_bounds__(256) void gemm_pair(GP g0, GP g1) {
  GP g = blockIdx.y ? g1 : g0;
  __shared__ bf16_t Xs[128][136];
  __shared__ bf16_t Wsh[128][136];
  const int t = threadIdx.x;
  const int row0 = blockIdx.x * 128;
  const int wave = t >> 6, lane = t & 63;
  const int lr = lane & 15, lk = (lane >> 4) * 8, mb = wave * 32;

  f32x4 acc[2][8];
  #pragma unroll
  for (int m = 0; m < 2; ++m)
    #pragma unroll
    for (int n = 0; n < 8; ++n) acc[m][n] = (f32x4){0.f, 0.f, 0.f, 0.f};

  #pragma unroll
  for (int ph = 0; ph < 2; ++ph) {
    const bf16_t* A = ph ? g.A1 : g.A0;
    const float* dD = ph ? g.dD1 : g.dD0;
    const bf16_t* W = ph ? g.W1 : g.W0;
    if (ph) __syncthreads();   // protect prior phase's LDS reads
    #pragma unroll
    for (int j = 0; j < 8; ++j) {
      int r = (t >> 4) + j * 16;
      int c = (t & 15) * 8;
      int gr = row0 + r;
      uint4 v = make_uint4(0u, 0u, 0u, 0u);
      float sc_ = 0.f;
      if (gr < NV) { v = *(const uint4*)(A + (size_t)gr * FD + c); sc_ = dD[gr]; }
      unsigned* pv = (unsigned*)&v;
      uint4 o;
      o.x = pk2(bflo(pv[0]) * sc_, bfhi(pv[0]) * sc_);
      o.y = pk2(bflo(pv[1]) * sc_, bfhi(pv[1]) * sc_);
      o.z = pk2(bflo(pv[2]) * sc_, bfhi(pv[2]) * sc_);
      o.w = pk2(bflo(pv[3]) * sc_, bfhi(pv[3]) * sc_);
      *(uint4*)&Xs[r][c] = o;
      *(uint4*)&Wsh[r][c] = *(const uint4*)(W + (size_t)r * FD + c);
    }
    __syncthreads();

    #pragma unroll
    for (int kc = 0; kc < 128; kc += 32) {
      bf16x8 a0 = *(const bf16x8*)&Xs[mb + lr][kc + lk];
      bf16x8 a1 = *(const bf16x8*)&Xs[mb + 16 + lr][kc + lk];
      bf16x8 b[8];
      #pragma unroll
      for (int n = 0; n < 8; ++n) b[n] = *(const bf16x8*)&Wsh[n * 16 + lr][kc + lk];
      #pragma unroll
      for (int n = 0; n < 8; ++n) {
        acc[0][n] = __builtin_amdgcn_mfma_f32_16x16x32_bf16(a0, b[n], acc[0][n], 0, 0, 0);
        acc[1][n] = __builtin_amdgcn_mfma_f32_16x16x32_bf16(a1, b[n], acc[1][n], 0, 0, 0);
      }
    }
  }

  // epilogue: +bias, relu, bf16, LDS transpose-stage, coalesced store
  float bc[8];
  #pragma unroll
  for (int n = 0; n < 8; ++n) {
    int col = n * 16 + lr;
    bc[n] = g.b0[col] + g.b1[col];
  }
  __syncthreads();
  const int rgrp = (lane >> 4) * 4;
  #pragma unroll
  for (int m = 0; m < 2; ++m)
    #pragma unroll
    for (int n = 0; n < 8; ++n)
      #pragma unroll
      for (int jj = 0; jj < 4; ++jj) {
        int rr = mb + m * 16 + rgrp + jj;
        Wsh[rr][n * 16 + lr] = f2bf(fmaxf(acc[m][n][jj] + bc[n], 0.f));
      }
  __syncthreads();
  #pragma unroll
  for (int j = 0; j < 8; ++j) {
    int r = (t >> 4) + j * 16;
    int c = (t & 15) * 8;
    int gr = row0 + r;
    if (gr < NV) *(uint4*)(g.Y + (size_t)gr * FD + c) = *(const uint4*)&Wsh[r][c];
  }
}

// ================= final linear: Out[NV,64] = X[NV,128] @ lw^T + lb =================
__global__ __launch_bounds__(256) void linear64(const bf16_t* __restrict__ Xb,
                                                const float* __restrict__ lw,
                                                const float* __restrict__ lb,
                                                float* __restrict__ Out) {
  __shared__ float Wt[128][68];
  __shared__ float Xs[64][132];
  const int tid = threadIdx.x;
  const int row0 = blockIdx.x * 64;

  for (int i = tid * 4; i < 64 * 128; i += 1024) {
    float4 v = *(const float4*)(lw + i);
    int o = i >> 7, h = i & 127;
    Wt[h + 0][o] = v.x; Wt[h + 1][o] = v.y; Wt[h + 2][o] = v.z; Wt[h + 3][o] = v.w;
  }
  for (int i = tid * 8; i < 64 * 128; i += 2048) {
    int rr = i >> 7, cc = i & 127;
    int gr = row0 + rr;
    uint4 v = make_uint4(0u, 0u, 0u, 0u);
    if (gr < NV) v = *(const uint4*)(Xb + (size_t)gr * FD + cc);
    unsigned* pv = (unsigned*)&v;
    #pragma unroll
    for (int q = 0; q < 4; ++q) {
      Xs[rr][cc + q * 2]     = bflo(pv[q]);
      Xs[rr][cc + q * 2 + 1] = bfhi(pv[q]);
    }
  }
  __syncthreads();

  const int tx = tid & 15, ty = tid >> 4;
  float acc[4][4];
  #pragma unroll
  for (int i = 0; i < 4; ++i)
    #pragma unroll
    for (int j = 0; j < 4; ++j) acc[i][j] = 0.f;

  for (int k = 0; k < 128; k += 4) {
    float4 xr[4], w[4];
    #pragma unroll
    for (int i = 0; i < 4; ++i) xr[i] = *(const float4*)&Xs[ty * 4 + i][k];
    #pragma unroll
    for (int j = 0; j < 4; ++j) w[j] = *(const float4*)&Wt[k + j][tx * 4];
    #pragma unroll
    for (int i = 0; i < 4; ++i) {
      const float* xv = (const float*)&xr[i];
      #pragma unroll
      for (int j = 0; j < 4; ++j) {
        float x = xv[j];
        acc[i][0] = fmaf(x, w[j].x, acc[i][0]);
        acc[i][1] = fmaf(x, w[j].y, acc[i][1]);
        acc[i][2] = fmaf(x, w[j].z, acc[i][2]);
        acc[i][3] = fmaf(x, w[j].w, acc[i][3]);
      }
    }
  }
  float4 bias = *(const float4*)(lb + tx * 4);
  #pragma unroll
  for (int i = 0; i < 4; ++i) {
    int gr = row0 + ty * 4 + i;
    if (gr < NV) {
      *(float4*)(Out + (size_t)gr * NOUT + tx * 4) =
          make_float4(acc[i][0] + bias.x, acc[i][1] + bias.y,
                      acc[i][2] + bias.z, acc[i][3] + bias.w);
    }
  }
}

// ================= host orchestration =================

extern "C" void kernel_launch(void* const* d_in, const int* in_sizes, int n_in,
                              void* d_out, int out_size, void* d_ws, size_t ws_size,
                              hipStream_t stream) {
  const float* x_drug = (const float*)d_in[0];
  const float* x_dis  = (const float*)d_in[1];
  const int* ei[4] = { (const int*)d_in[2], (const int*)d_in[3],
                       (const int*)d_in[4], (const int*)d_in[5] };  // dd, ss, ds, sd
  const float* Ws = (const float*)d_in[6];
  const float* bs = (const float*)d_in[7];
  const float* lw = (const float*)d_in[8];
  const float* lb = (const float*)d_in[9];
  float* out = (float*)d_out;

  char* p = (char*)d_ws;
  auto take = [&](size_t bytes) -> void* {
    char* q = p;
    p += (bytes + 255) & ~(size_t)255;
    return (void*)q;
  };
  int* blockCnt   = (int*)take((size_t)4 * SCAN_L * sizeof(int));     // 1.23MB
  int* chunkSum   = (int*)take((size_t)4 * NSCH * sizeof(int));
  int* srcBase    = (int*)take((size_t)4 * (NBIN + 1) * sizeof(int));
  unsigned* pairS = (unsigned*)take((size_t)4 * NE * sizeof(unsigned)); // 12.8MB
  int* blockCnt2  = (int*)take((size_t)4 * SCAN_L2 * sizeof(int));    // 4.9MB
  int* chunkSum2  = (int*)take((size_t)4 * NSCH2 * sizeof(int));
  int* bb2        = (int*)take((size_t)4 * (NBIN2 + 1) * sizeof(int));
  unsigned* edge2 = (unsigned*)take((size_t)4 * NE * sizeof(unsigned)); // 12.8MB
  float* dinvS    = (float*)take((size_t)4 * NV * sizeof(float));
  float* dDall    = (float*)take((size_t)4 * NV * sizeof(float));
  bf16_t* agg     = (bf16_t*)take((size_t)4 * NV * FD * sizeof(bf16_t)); // 51.2MB
  bf16_t* xdb = (bf16_t*)take((size_t)NV * FD * sizeof(bf16_t));
  bf16_t* xsb = (bf16_t*)take((size_t)NV * FD * sizeof(bf16_t));
  bf16_t* Wtb = (bf16_t*)take((size_t)8 * FD * FD * sizeof(bf16_t));
  bf16_t* XD1 = (bf16_t*)take((size_t)NV * FD * sizeof(bf16_t));
  bf16_t* XS1 = (bf16_t*)take((size_t)NV * FD * sizeof(bf16_t));
  bf16_t* XD2 = (bf16_t*)take((size_t)NV * FD * sizeof(bf16_t));
  bf16_t* XS2 = (bf16_t*)take((size_t)NV * FD * sizeof(bf16_t));

  Ptr4 rows = {{ ei[0], ei[1], ei[2], ei[3] }};
  Ptr4 cols = {{ ei[0] + NE, ei[1] + NE, ei[2] + NE, ei[3] + NE }};

  // ---- prep: two-stage bucket sort -> src-sorted per-dst-bucket edge streams ----
  p0s_hist<<<dim3(NBLK, 4), 256, 0, stream>>>(rows, blockCnt);
  t_pass1<SCAN_L, NSCH><<<dim3(NSCH, 4), 256, 0, stream>>>(blockCnt, chunkSum);
  t_pass2<4, NSCH, NBIN><<<1, 1024, 0, stream>>>(chunkSum, srcBase);
  t_pass3<SCAN_L, NSCH, NBIN><<<dim3(NSCH, 4), 256, 0, stream>>>(blockCnt, chunkSum, srcBase);
  p1s_scatter<<<dim3(NBLK, 4), 256, 0, stream>>>(rows, cols, blockCnt, pairS);
  p2_srcdeg<<<dim3(NBIN, 4), 256, 0, stream>>>(pairS, srcBase, dinvS);
  p0d2<<<dim3(NBLK, 4), 256, 0, stream>>>(pairS, blockCnt2);
  t_pass1<SCAN_L2, NSCH2><<<dim3(NSCH2, 4), 256, 0, stream>>>(blockCnt2, chunkSum2);
  t_pass2<4, NSCH2, NBIN2><<<1, 1024, 0, stream>>>(chunkSum2, bb2);
  t_pass3<SCAN_L2, NSCH2, NBIN2><<<dim3(NSCH2, 4), 256, 0, stream>>>(blockCnt2, chunkSum2, bb2);
  p1d2<<<dim3(NBLK, 4), 256, 0, stream>>>(pairS, blockCnt2, edge2);
  xcvt<<<(NV * FD / 4 + 255) / 256, 256, 0, stream>>>(x_drug, xdb, NV * FD / 4);
  xcvt<<<(NV * FD / 4 + 255) / 256, 256, 0, stream>>>(x_dis, xsb, NV * FD / 4);
  wprep<<<(8 * FD * FD + 255) / 256, 256, 0, stream>>>(Ws, Wtb);

  // ---- layers ----
  const dim3 PULL_GRID(NBIN2, 2);
  const dim3 GEMM_GRID((NV + 127) / 128, 2);
  const int LIN_GRID = (NV + 63) / 64;
  const bf16_t* xd = xdb;
  const bf16_t* xs = xsb;
  bf16_t* nextd[2] = {XD1, XD2};
  bf16_t* nexts[2] = {XS1, XS2};
  for (int l = 0; l < 2; ++l) {
    pull_push<<<PULL_GRID, 512, 0, stream>>>(xd, xs, edge2, bb2, dinvS, agg, dDall);

    GP gd;  // drug: r0 (dd) + r3 (sd)
    gd.A0 = agg + (size_t)0 * NV * FD; gd.dD0 = dDall + 0 * NV;
    gd.W0 = Wtb + (size_t)(l * 4 + 0) * FD * FD;
    gd.A1 = agg + (size_t)3 * NV * FD; gd.dD1 = dDall + 3 * NV;
    gd.W1 = Wtb + (size_t)(l * 4 + 3) * FD * FD;
    gd.b0 = bs + (l * 4 + 0) * FD; gd.b1 = bs + (l * 4 + 3) * FD;
    gd.Y = nextd[l];
    GP gs;  // dis: r1 (ss) + r2 (ds)
    gs.A0 = agg + (size_t)1 * NV * FD; gs.dD0 = dDall + 1 * NV;
    gs.W0 = Wtb + (size_t)(l * 4 + 1) * FD * FD;
    gs.A1 = agg + (size_t)2 * NV * FD; gs.dD1 = dDall + 2 * NV;
    gs.W1 = Wtb + (size_t)(l * 4 + 2) * FD * FD;
    gs.b0 = bs + (l * 4 + 1) * FD; gs.b1 = bs + (l * 4 + 2) * FD;
    gs.Y = nexts[l];
    gemm_pair<<<GEMM_GRID, 256, 0, stream>>>(gd, gs);

    xd = nextd[l];
    xs = nexts[l];
  }

  linear64<<<LIN_GRID, 256, 0, stream>>>(xd, lw, lb, out);
  linear64<<<LIN_GRID, 256, 0, stream>>>(xs, lw, lb, out + (size_t)NV * NOUT);
}

// Round 9
// 434.445 us; speedup vs baseline: 11.6254x; 11.6254x over previous
//
#include <hip/hip_runtime.h>

#define NV   50000
#define FD   128
#define NE   800000
#define NOUT 64
#define NBIN 196          // ceil(NV/256) coarse buckets of 256 nodes
#define CH   2048         // edges per block in P0/P1
#define NBLK 391          // ceil(NE/CH)
#define SCAN_L (NBIN * NBLK)
#define SCHUNK 2048       // elements per block in hierarchical scan
#define NSCH ((SCAN_L + SCHUNK - 1) / SCHUNK)   // 38
#define CAP2 12288        // LDS staging cap in P2 (avg span ~4083)

typedef unsigned short bf16_t;
typedef unsigned char  u8;
typedef __attribute__((ext_vector_type(8))) short bf16x8;
typedef __attribute__((ext_vector_type(4))) float f32x4;

__device__ __forceinline__ bf16_t f2bf(float f) {
  unsigned u = __builtin_bit_cast(unsigned, f);
  return (bf16_t)((u + 0x7fffu + ((u >> 16) & 1u)) >> 16);
}
__device__ __forceinline__ float bflo(unsigned v) { return __builtin_bit_cast(float, v << 16); }
__device__ __forceinline__ float bfhi(unsigned v) { return __builtin_bit_cast(float, v & 0xffff0000u); }
__device__ __forceinline__ unsigned pk2(float a, float b) {
  return (unsigned)f2bf(a) | ((unsigned)f2bf(b) << 16);
}

struct Ptr4 { const int* p[4]; };

// ================= bucket-sort based CSR build (no global atomics) =================

__global__ __launch_bounds__(256) void p0_hist(Ptr4 rows, Ptr4 cols,
                                               int* __restrict__ blockCnt) {
  const int r = blockIdx.y, blk = blockIdx.x, t = threadIdx.x;
  __shared__ int cd[NBIN], cs[NBIN];
  for (int i = t; i < NBIN; i += 256) { cd[i] = 0; cs[i] = 0; }
  __syncthreads();
  const int e0 = blk * CH;
  const int n = min(CH, NE - e0);
  const int* rw = rows.p[r] + e0;
  const int* cl = cols.p[r] + e0;
  for (int i = t; i < n; i += 256) {
    atomicAdd(&cd[cl[i] >> 8], 1);
    atomicAdd(&cs[rw[i] >> 8], 1);
  }
  __syncthreads();
  int* bd = blockCnt + (size_t)(r * 2 + 0) * SCAN_L;
  int* bs = blockCnt + (size_t)(r * 2 + 1) * SCAN_L;
  for (int i = t; i < NBIN; i += 256) {
    bd[i * NBLK + blk] = cd[i];
    bs[i * NBLK + blk] = cs[i];
  }
}

__global__ __launch_bounds__(256) void scan_pass1(const int* __restrict__ blockCnt,
                                                  int* __restrict__ chunkSum) {
  const int r2 = blockIdx.y, chunk = blockIdx.x, t = threadIdx.x;
  const int* a = blockCnt + (size_t)r2 * SCAN_L + chunk * SCHUNK;
  const int n = min(SCHUNK, SCAN_L - chunk * SCHUNK);
  int s = 0;
  for (int i = t; i < n; i += 256) s += a[i];
  __shared__ int sm[256];
  sm[t] = s;
  __syncthreads();
  #pragma unroll
  for (int off = 128; off > 0; off >>= 1) {
    if (t < off) sm[t] += sm[t + off];
    __syncthreads();
  }
  if (t == 0) chunkSum[r2 * NSCH + chunk] = sm[0];
}

__global__ __launch_bounds__(512) void scan_pass2(int* __restrict__ chunkSum,
                                                  int* __restrict__ bucketBase) {
  const int t = threadIdx.x;
  __shared__ int sm[8 * NSCH];
  if (t < 8 * NSCH) sm[t] = chunkSum[t];
  __syncthreads();
  if (t < 8) {
    int run = 0;
    for (int j = 0; j < NSCH; ++j) {
      int v = sm[t * NSCH + j];
      sm[t * NSCH + j] = run;
      run += v;
    }
    bucketBase[t * (NBIN + 1) + NBIN] = NE;
  }
  __syncthreads();
  if (t < 8 * NSCH) chunkSum[t] = sm[t];
}

__global__ __launch_bounds__(256) void scan_pass3(int* __restrict__ blockCnt,
                                                  const int* __restrict__ chunkSum,
                                                  int* __restrict__ bucketBase) {
  const int r2 = blockIdx.y, chunk = blockIdx.x, t = threadIdx.x;
  int* a = blockCnt + (size_t)r2 * SCAN_L + chunk * SCHUNK;
  const int gbase = chunk * SCHUNK;
  const int n = min(SCHUNK, SCAN_L - gbase);
  const int idx0 = t * 8;
  int v[8];
  int s = 0;
  #pragma unroll
  for (int j = 0; j < 8; ++j) {
    int id = idx0 + j;
    v[j] = (id < n) ? a[id] : 0;
    s += v[j];
  }
  __shared__ int sm[256];
  sm[t] = s;
  __syncthreads();
  for (int off = 1; off < 256; off <<= 1) {
    int x = (t >= off) ? sm[t - off] : 0;
    __syncthreads();
    sm[t] += x;
    __syncthreads();
  }
  int pre = ((t == 0) ? 0 : sm[t - 1]) + chunkSum[r2 * NSCH + chunk];
  #pragma unroll
  for (int j = 0; j < 8; ++j) {
    int id = idx0 + j;
    if (id < n) {
      int val = v[j];
      a[id] = pre;
      int g = gbase + id;
      if (g % NBLK == 0) bucketBase[r2 * (NBIN + 1) + g / NBLK] = pre;
      pre += val;
    }
  }
}

__global__ __launch_bounds__(256) void p1_scatter(Ptr4 rows, Ptr4 cols,
                                                  const int* __restrict__ blockCnt,
                                                  unsigned* __restrict__ pairD,
                                                  u8* __restrict__ srcb) {
  const int r = blockIdx.y, blk = blockIdx.x, t = threadIdx.x;
  const int e0 = blk * CH;
  const int n = min(CH, NE - e0);
  const int* rw = rows.p[r] + e0;
  const int* cl = cols.p[r] + e0;

  __shared__ int cnt[256], sc[256], lofs[256], cnt2[256], baseT[256];
  __shared__ unsigned pr[CH];
  __shared__ u8 binb[CH];
  __shared__ u8 pay8[CH];

  // ---------- dst side ----------
  cnt[t] = 0; cnt2[t] = 0;
  __syncthreads();
  for (int i = t; i < n; i += 256) atomicAdd(&cnt[cl[i] >> 8], 1);
  __syncthreads();
  sc[t] = cnt[t];
  __syncthreads();
  for (int off = 1; off < 256; off <<= 1) {
    int v = (t >= off) ? sc[t - off] : 0;
    __syncthreads();
    sc[t] += v;
    __syncthreads();
  }
  lofs[t] = (t == 0) ? 0 : sc[t - 1];
  if (t < NBIN) baseT[t] = blockCnt[(size_t)(r * 2 + 0) * SCAN_L + t * NBLK + blk];
  __syncthreads();
  for (int i = t; i < n; i += 256) {
    int c = cl[i];
    int bin = c >> 8;
    int rank = atomicAdd(&cnt2[bin], 1);
    int p = lofs[bin] + rank;
    pr[p] = ((unsigned)(c & 255) << 16) | (unsigned)rw[i];
    binb[p] = (u8)bin;
  }
  __syncthreads();
  {
    unsigned* pd = pairD + (size_t)r * NE;
    for (int i = t; i < n; i += 256) {
      int bin = binb[i];
      pd[baseT[bin] + (i - lofs[bin])] = pr[i];
    }
  }
  __syncthreads();

  // ---------- src side ----------
  cnt[t] = 0; cnt2[t] = 0;
  __syncthreads();
  for (int i = t; i < n; i += 256) atomicAdd(&cnt[rw[i] >> 8], 1);
  __syncthreads();
  sc[t] = cnt[t];
  __syncthreads();
  for (int off = 1; off < 256; off <<= 1) {
    int v = (t >= off) ? sc[t - off] : 0;
    __syncthreads();
    sc[t] += v;
    __syncthreads();
  }
  lofs[t] = (t == 0) ? 0 : sc[t - 1];
  if (t < NBIN) baseT[t] = blockCnt[(size_t)(r * 2 + 1) * SCAN_L + t * NBLK + blk];
  __syncthreads();
  for (int i = t; i < n; i += 256) {
    int sv = rw[i];
    int bin = sv >> 8;
    int rank = atomicAdd(&cnt2[bin], 1);
    int p = lofs[bin] + rank;
    pay8[p] = (u8)(sv & 255);
    binb[p] = (u8)bin;
  }
  __syncthreads();
  {
    u8* sb = srcb + (size_t)r * NE;
    for (int i = t; i < n; i += 256) {
      int bin = binb[i];
      sb[baseT[bin] + (i - lofs[bin])] = pay8[i];
    }
  }
}

// P2: per dst-bucket -> rowptr, dinvD, and node-sorted srcidx (int32)
__global__ __launch_bounds__(256) void p2_csr(const unsigned* __restrict__ pairD,
                                              const int* __restrict__ bucketBase,
                                              int* __restrict__ srcidx,
                                              int* __restrict__ rowptr,
                                              float* __restrict__ dinvD) {
  const int r = blockIdx.y, bin = blockIdx.x, t = threadIdx.x;
  const int* bb = bucketBase + (r * 2 + 0) * (NBIN + 1);
  const int base = bb[bin], next = bb[bin + 1];
  const int span = next - base;
  const unsigned* pd = pairD + (size_t)r * NE + base;

  __shared__ int cnt[256], sc[256], ex[256], cnt2[256];
  __shared__ int lsrc[CAP2];
  cnt[t] = 0; cnt2[t] = 0;
  __syncthreads();
  for (int i = t; i < span; i += 256) atomicAdd(&cnt[pd[i] >> 16], 1);
  __syncthreads();
  sc[t] = cnt[t];
  __syncthreads();
  for (int off = 1; off < 256; off <<= 1) {
    int v = (t >= off) ? sc[t - off] : 0;
    __syncthreads();
    sc[t] += v;
    __syncthreads();
  }
  ex[t] = (t == 0) ? 0 : sc[t - 1];
  __syncthreads();

  const int node = (bin << 8) + t;
  if (node < NV) {
    rowptr[r * (NV + 1) + node] = base + ex[t];
    float deg = (float)cnt[t];
    dinvD[r * NV + node] = (r < 2) ? rsqrtf(deg + 1.f)
                                   : (deg > 0.f ? rsqrtf(deg) : 0.f);
  }
  if (bin == NBIN - 1 && t == 0) rowptr[r * (NV + 1) + NV] = NE;

  int* so = srcidx + (size_t)r * NE + base;
  if (span <= CAP2) {
    for (int i = t; i < span; i += 256) {
      unsigned v = pd[i];
      int dl = v >> 16;
      int rank = atomicAdd(&cnt2[dl], 1);
      lsrc[ex[dl] + rank] = (int)(v & 0xFFFFu);
    }
    __syncthreads();
    for (int i = t; i < span; i += 256) so[i] = lsrc[i];
  } else {
    for (int i = t; i < span; i += 256) {
      unsigned v = pd[i];
      int dl = v >> 16;
      int rank = atomicAdd(&cnt2[dl], 1);
      so[ex[dl] + rank] = (int)(v & 0xFFFFu);
    }
  }
}

__global__ __launch_bounds__(256) void p2_srcdeg(const u8* __restrict__ srcb,
                                                 const int* __restrict__ bucketBase,
                                                 float* __restrict__ dinvS) {
  const int r = blockIdx.y, bin = blockIdx.x, t = threadIdx.x;
  const int* bb = bucketBase + (r * 2 + 1) * (NBIN + 1);
  const int base = bb[bin], next = bb[bin + 1];
  const int span = next - base;
  const u8* sb = srcb + (size_t)r * NE + base;
  __shared__ int cnt[256];
  cnt[t] = 0;
  __syncthreads();
  for (int i = t; i < span; i += 256) atomicAdd(&cnt[sb[i]], 1);
  __syncthreads();
  int node = (bin << 8) + t;
  if (node < NV) {
    float deg = (float)cnt[t];
    dinvS[r * NV + node] = (r < 2) ? rsqrtf(deg + 1.f)
                                   : (deg > 0.f ? rsqrtf(deg) : 0.f);
  }
}

// ================= dtype prep =================

__global__ __launch_bounds__(256) void xcvt(const float* __restrict__ x,
                                            bf16_t* __restrict__ xb, int n4) {
  int i = blockIdx.x * 256 + threadIdx.x;
  if (i < n4) {
    float4 v = *(const float4*)(x + (size_t)i * 4);
    *(uint2*)(xb + (size_t)i * 4) = make_uint2(pk2(v.x, v.y), pk2(v.z, v.w));
  }
}

// W[8][128k][128n] fp32 -> Wt[8][128n][128k] bf16 (transposed)
__global__ __launch_bounds__(256) void wprep(const float* __restrict__ Wsrc,
                                             bf16_t* __restrict__ Wt) {
  int idx = blockIdx.x * 256 + threadIdx.x;
  if (idx < 8 * 128 * 128) {
    int i = idx >> 14, n = (idx >> 7) & 127, k = idx & 127;
    Wt[idx] = f2bf(Wsrc[(size_t)i * 16384 + k * 128 + n]);
  }
}

// ================= MFMA quad GEMM: H = bf16( dS * (Xb @ W) ), row-major H ======
struct G4 {
  const bf16_t* X[4];
  const bf16_t* W[4];
  const float*  dS[4];
  bf16_t*       H[4];
};

__global__ __launch_bounds__(256) void gemm_quad(G4 g) {
  const int q = blockIdx.y;
  const bf16_t* Xb = g.X[q]; const bf16_t* Wt = g.W[q];
  const float* dS = g.dS[q]; bf16_t* H = g.H[q];

  __shared__ bf16_t Xs[128][136];
  __shared__ bf16_t Wsh[128][136];
  __shared__ float sdS[128];
  const int t = threadIdx.x;
  const int row0 = blockIdx.x * 128;

  #pragma unroll
  for (int j = 0; j < 8; ++j) {
    int r = (t >> 4) + j * 16;
    int c = (t & 15) * 8;
    int gr = row0 + r;
    uint4 v = make_uint4(0u, 0u, 0u, 0u);
    if (gr < NV) v = *(const uint4*)(Xb + (size_t)gr * FD + c);
    *(uint4*)&Xs[r][c] = v;
    *(uint4*)&Wsh[r][c] = *(const uint4*)(Wt + (size_t)r * FD + c);
  }
  if (t < 128) {
    int gidx = row0 + t;
    sdS[t] = (gidx < NV) ? dS[gidx] : 0.f;
  }
  __syncthreads();

  const int wave = t >> 6, lane = t & 63;
  const int lr = lane & 15;
  const int lk = (lane >> 4) * 8;
  const int mb = wave * 32;

  f32x4 acc[2][8];
  #pragma unroll
  for (int m = 0; m < 2; ++m)
    #pragma unroll
    for (int n = 0; n < 8; ++n) acc[m][n] = (f32x4){0.f, 0.f, 0.f, 0.f};

  #pragma unroll
  for (int kc = 0; kc < 128; kc += 32) {
    bf16x8 a0 = *(const bf16x8*)&Xs[mb + lr][kc + lk];
    bf16x8 a1 = *(const bf16x8*)&Xs[mb + 16 + lr][kc + lk];
    bf16x8 b[8];
    #pragma unroll
    for (int n = 0; n < 8; ++n) b[n] = *(const bf16x8*)&Wsh[n * 16 + lr][kc + lk];
    #pragma unroll
    for (int n = 0; n < 8; ++n) {
      acc[0][n] = __builtin_amdgcn_mfma_f32_16x16x32_bf16(a0, b[n], acc[0][n], 0, 0, 0);
      acc[1][n] = __builtin_amdgcn_mfma_f32_16x16x32_bf16(a1, b[n], acc[1][n], 0, 0, 0);
    }
  }

  __syncthreads();   // done reading Wsh; reuse as bf16 output staging
  const int rgrp = (lane >> 4) * 4;
  #pragma unroll
  for (int m = 0; m < 2; ++m)
    #pragma unroll
    for (int n = 0; n < 8; ++n)
      #pragma unroll
      for (int j = 0; j < 4; ++j) {
        int rr = mb + m * 16 + rgrp + j;
        Wsh[rr][n * 16 + lr] = f2bf(acc[m][n][j] * sdS[rr]);
      }
  __syncthreads();

  #pragma unroll
  for (int j = 0; j < 8; ++j) {
    int r = (t >> 4) + j * 16;
    int c = (t & 15) * 8;
    int gr = row0 + r;
    if (gr < NV) *(uint4*)(H + (size_t)gr * FD + c) = *(const uint4*)&Wsh[r][c];
  }
}

// ================= fused dual pull aggregation (pair-edge gathers) =================
// One wave per node. Lane split: el = lane>>5 (edge of pair), dl = lane&31
// (4 dims via one 8B load). 8 pair-loads in flight -> 16 edges / 4KB per wave.
__device__ __forceinline__ void acc4(uint2 v, float& x0, float& x1, float& x2, float& x3) {
  x0 += bflo(v.x); x1 += bfhi(v.x); x2 += bflo(v.y); x3 += bfhi(v.y);
}

__device__ __forceinline__ void gather_pair(const bf16_t* __restrict__ h,
                                            const int* __restrict__ src,
                                            int p0, int p1, int el, int d,
                                            float& x0, float& x1, float& x2, float& x3) {
  int p = p0;
  while (p + 16 <= p1) {
    int s0 = src[p + 0 + el],  s1 = src[p + 2 + el],  s2 = src[p + 4 + el],  s3 = src[p + 6 + el];
    int s4 = src[p + 8 + el],  s5 = src[p + 10 + el], s6 = src[p + 12 + el], s7 = src[p + 14 + el];
    uint2 v0 = *(const uint2*)(h + (s0 << 7) + d);
    uint2 v1 = *(const uint2*)(h + (s1 << 7) + d);
    uint2 v2 = *(const uint2*)(h + (s2 << 7) + d);
    uint2 v3 = *(const uint2*)(h + (s3 << 7) + d);
    uint2 v4 = *(const uint2*)(h + (s4 << 7) + d);
    uint2 v5 = *(const uint2*)(h + (s5 << 7) + d);
    uint2 v6 = *(const uint2*)(h + (s6 << 7) + d);
    uint2 v7 = *(const uint2*)(h + (s7 << 7) + d);
    acc4(v0, x0, x1, x2, x3); acc4(v1, x0, x1, x2, x3);
    acc4(v2, x0, x1, x2, x3); acc4(v3, x0, x1, x2, x3);
    acc4(v4, x0, x1, x2, x3); acc4(v5, x0, x1, x2, x3);
    acc4(v6, x0, x1, x2, x3); acc4(v7, x0, x1, x2, x3);
    p += 16;
  }
  while (p + 8 <= p1) {
    int s0 = src[p + 0 + el], s1 = src[p + 2 + el], s2 = src[p + 4 + el], s3 = src[p + 6 + el];
    uint2 v0 = *(const uint2*)(h + (s0 << 7) + d);
    uint2 v1 = *(const uint2*)(h + (s1 << 7) + d);
    uint2 v2 = *(const uint2*)(h + (s2 << 7) + d);
    uint2 v3 = *(const uint2*)(h + (s3 << 7) + d);
    acc4(v0, x0, x1, x2, x3); acc4(v1, x0, x1, x2, x3);
    acc4(v2, x0, x1, x2, x3); acc4(v3, x0, x1, x2, x3);
    p += 8;
  }
  while (p + 2 <= p1) {
    int s = src[p + el];
    uint2 v = *(const uint2*)(h + (s << 7) + d);
    acc4(v, x0, x1, x2, x3);
    p += 2;
  }
  if (p < p1 && el == 0) {   // odd remainder handled by el=0 half only
    int s = src[p];
    uint2 v = *(const uint2*)(h + (s << 7) + d);
    acc4(v, x0, x1, x2, x3);
  }
}

struct PullSide {
  const bf16_t* hA; const int* rpA; const int* srcA; const float* dDA;
  const bf16_t* hB; const int* rpB; const int* srcB; const float* dDB;
  const float* bA; const float* bB; bf16_t* Y;
};

__global__ __launch_bounds__(256) void pull_dual(PullSide s0, PullSide s1) {
  const PullSide& a = blockIdx.y ? s1 : s0;
  const int i = __builtin_amdgcn_readfirstlane(blockIdx.x * 4 + (threadIdx.x >> 6));
  if (i >= NV) return;
  const int lane = threadIdx.x & 63;
  const int el = lane >> 5;        // which edge of the pair
  const int d = (lane & 31) * 4;   // 4 dims per lane

  float a0 = 0.f, a1 = 0.f, a2 = 0.f, a3 = 0.f;
  if (el == 0) {  // self-loop (relation A homogeneous; h pre-scaled by dS)
    uint2 v = *(const uint2*)(a.hA + (i << 7) + d);
    acc4(v, a0, a1, a2, a3);
  }
  gather_pair(a.hA, a.srcA, a.rpA[i], a.rpA[i + 1], el, d, a0, a1, a2, a3);
  float b0 = 0.f, b1 = 0.f, b2 = 0.f, b3 = 0.f;
  gather_pair(a.hB, a.srcB, a.rpB[i], a.rpB[i + 1], el, d, b0, b1, b2, b3);

  // merge the two edge-halves (lane ^ 32 holds the partner partial)
  a0 += __shfl_xor(a0, 32, 64); a1 += __shfl_xor(a1, 32, 64);
  a2 += __shfl_xor(a2, 32, 64); a3 += __shfl_xor(a3, 32, 64);
  b0 += __shfl_xor(b0, 32, 64); b1 += __shfl_xor(b1, 32, 64);
  b2 += __shfl_xor(b2, 32, 64); b3 += __shfl_xor(b3, 32, 64);

  if (el == 0) {   // lanes 0..31 write the 256B row
    float wA = a.dDA[i], wB = a.dDB[i];
    float4 ba = *(const float4*)(a.bA + d);
    float4 bb = *(const float4*)(a.bB + d);
    float o0 = fmaf(a0, wA, fmaf(b0, wB, ba.x + bb.x));
    float o1 = fmaf(a1, wA, fmaf(b1, wB, ba.y + bb.y));
    float o2 = fmaf(a2, wA, fmaf(b2, wB, ba.z + bb.z));
    float o3 = fmaf(a3, wA, fmaf(b3, wB, ba.w + bb.w));
    *(uint2*)(a.Y + (size_t)i * FD + d) =
        make_uint2(pk2(fmaxf(o0, 0.f), fmaxf(o1, 0.f)),
                   pk2(fmaxf(o2, 0.f), fmaxf(o3, 0.f)));
  }
}

// ================= final linear: Out[NV,64] = X[NV,128] @ lw^T + lb =================
__global__ __launch_bounds__(256) void linear64(const bf16_t* __restrict__ Xb,
                                                const float* __restrict__ lw,
                                                const float* __restrict__ lb,
                                                float* __restrict__ Out) {
  __shared__ float Wt[128][68];
  __shared__ float Xs[64][132];
  const int tid = threadIdx.x;
  const int row0 = blockIdx.x * 64;

  for (int i = tid * 4; i < 64 * 128; i += 1024) {
    float4 v = *(const float4*)(lw + i);
    int o = i >> 7, h = i & 127;
    Wt[h + 0][o] = v.x; Wt[h + 1][o] = v.y; Wt[h + 2][o] = v.z; Wt[h + 3][o] = v.w;
  }
  for (int i = tid * 8; i < 64 * 128; i += 2048) {
    int rr = i >> 7, cc = i & 127;
    int gr = row0 + rr;
    uint4 v = make_uint4(0u, 0u, 0u, 0u);
    if (gr < NV) v = *(const uint4*)(Xb + (size_t)gr * FD + cc);
    unsigned* pv = (unsigned*)&v;
    #pragma unroll
    for (int q = 0; q < 4; ++q) {
      Xs[rr][cc + q * 2]     = bflo(pv[q]);
      Xs[rr][cc + q * 2 + 1] = bfhi(pv[q]);
    }
  }
  __syncthreads();

  const int tx = tid & 15, ty = tid >> 4;
  float acc[4][4];
  #pragma unroll
  for (int i = 0; i < 4; ++i)
    #pragma unroll
    for (int j = 0; j < 4; ++j) acc[i][j] = 0.f;

  for (int k = 0; k < 128; k += 4) {
    float4 xr[4], w[4];
    #pragma unroll
    for (int i = 0; i < 4; ++i) xr[i] = *(const float4*)&Xs[ty * 4 + i][k];
    #pragma unroll
    for (int j = 0; j < 4; ++j) w[j] = *(const float4*)&Wt[k + j][tx * 4];
    #pragma unroll
    for (int i = 0; i < 4; ++i) {
      const float* xv = (const float*)&xr[i];
      #pragma unroll
      for (int j = 0; j < 4; ++j) {
        float x = xv[j];
        acc[i][0] = fmaf(x, w[j].x, acc[i][0]);
        acc[i][1] = fmaf(x, w[j].y, acc[i][1]);
        acc[i][2] = fmaf(x, w[j].z, acc[i][2]);
        acc[i][3] = fmaf(x, w[j].w, acc[i][3]);
      }
    }
  }
  float4 bias = *(const float4*)(lb + tx * 4);
  #pragma unroll
  for (int i = 0; i < 4; ++i) {
    int gr = row0 + ty * 4 + i;
    if (gr < NV) {
      *(float4*)(Out + (size_t)gr * NOUT + tx * 4) =
          make_float4(acc[i][0] + bias.x, acc[i][1] + bias.y,
                      acc[i][2] + bias.z, acc[i][3] + bias.w);
    }
  }
}

// ================= host orchestration =================

extern "C" void kernel_launch(void* const* d_in, const int* in_sizes, int n_in,
                              void* d_out, int out_size, void* d_ws, size_t ws_size,
                              hipStream_t stream) {
  const float* x_drug = (const float*)d_in[0];
  const float* x_dis  = (const float*)d_in[1];
  const int* ei[4] = { (const int*)d_in[2], (const int*)d_in[3],
                       (const int*)d_in[4], (const int*)d_in[5] };  // dd, ss, ds, sd
  const float* Ws = (const float*)d_in[6];
  const float* bs = (const float*)d_in[7];
  const float* lw = (const float*)d_in[8];
  const float* lb = (const float*)d_in[9];
  float* out = (float*)d_out;

  char* p = (char*)d_ws;
  auto take = [&](size_t bytes) -> void* {
    char* q = p;
    p += (bytes + 255) & ~(size_t)255;
    return (void*)q;
  };
  int* blockCnt   = (int*)take((size_t)8 * SCAN_L * sizeof(int));
  int* chunkSum   = (int*)take((size_t)8 * NSCH * sizeof(int));
  int* bucketBase = (int*)take((size_t)8 * (NBIN + 1) * sizeof(int));
  unsigned* pairD = (unsigned*)take((size_t)4 * NE * sizeof(unsigned));
  u8* srcb        = (u8*)take((size_t)4 * NE);
  int* srcidx     = (int*)take((size_t)4 * NE * sizeof(int));
  int* rowptr     = (int*)take((size_t)4 * (NV + 1) * sizeof(int));
  float* dinvS    = (float*)take((size_t)4 * NV * sizeof(float));
  float* dinvD    = (float*)take((size_t)4 * NV * sizeof(float));
  bf16_t* hA  = (bf16_t*)take((size_t)NV * FD * sizeof(bf16_t));
  bf16_t* hB  = (bf16_t*)take((size_t)NV * FD * sizeof(bf16_t));
  bf16_t* hC  = (bf16_t*)take((size_t)NV * FD * sizeof(bf16_t));
  bf16_t* hD  = (bf16_t*)take((size_t)NV * FD * sizeof(bf16_t));
  bf16_t* xdb = (bf16_t*)take((size_t)NV * FD * sizeof(bf16_t));
  bf16_t* xsb = (bf16_t*)take((size_t)NV * FD * sizeof(bf16_t));
  bf16_t* Wtb = (bf16_t*)take((size_t)8 * FD * FD * sizeof(bf16_t));
  bf16_t* XD1 = (bf16_t*)take((size_t)NV * FD * sizeof(bf16_t));
  bf16_t* XS1 = (bf16_t*)take((size_t)NV * FD * sizeof(bf16_t));
  bf16_t* XD2 = (bf16_t*)take((size_t)NV * FD * sizeof(bf16_t));
  bf16_t* XS2 = (bf16_t*)take((size_t)NV * FD * sizeof(bf16_t));

  Ptr4 rows = {{ ei[0], ei[1], ei[2], ei[3] }};
  Ptr4 cols = {{ ei[0] + NE, ei[1] + NE, ei[2] + NE, ei[3] + NE }};

  // ---- prep ----
  p0_hist<<<dim3(NBLK, 4), 256, 0, stream>>>(rows, cols, blockCnt);
  scan_pass1<<<dim3(NSCH, 8), 256, 0, stream>>>(blockCnt, chunkSum);
  scan_pass2<<<1, 512, 0, stream>>>(chunkSum, bucketBase);
  scan_pass3<<<dim3(NSCH, 8), 256, 0, stream>>>(blockCnt, chunkSum, bucketBase);
  p1_scatter<<<dim3(NBLK, 4), 256, 0, stream>>>(rows, cols, blockCnt, pairD, srcb);
  p2_csr<<<dim3(NBIN, 4), 256, 0, stream>>>(pairD, bucketBase, srcidx, rowptr, dinvD);
  p2_srcdeg<<<dim3(NBIN, 4), 256, 0, stream>>>(srcb, bucketBase, dinvS);
  xcvt<<<(NV * FD / 4 + 255) / 256, 256, 0, stream>>>(x_drug, xdb, NV * FD / 4);
  xcvt<<<(NV * FD / 4 + 255) / 256, 256, 0, stream>>>(x_dis, xsb, NV * FD / 4);
  wprep<<<(8 * FD * FD + 255) / 256, 256, 0, stream>>>(Ws, Wtb);

  // ---- layers ----
  const dim3 GEMM_GRID((NV + 127) / 128, 4);   // 391 x 4
  const dim3 PULL_GRID((NV + 3) / 4, 2);       // 12500 x 2
  const int LIN_GRID = (NV + 63) / 64;
  const bf16_t* xd = xdb;
  const bf16_t* xs = xsb;
  bf16_t* nextd[2] = {XD1, XD2};
  bf16_t* nexts[2] = {XS1, XS2};
  for (int l = 0; l < 2; ++l) {
    const bf16_t* W0 = Wtb + (size_t)(l * 4 + 0) * FD * FD;
    const bf16_t* W1 = Wtb + (size_t)(l * 4 + 1) * FD * FD;
    const bf16_t* W2 = Wtb + (size_t)(l * 4 + 2) * FD * FD;
    const bf16_t* W3 = Wtb + (size_t)(l * 4 + 3) * FD * FD;
    const float* b0 = bs + (l * 4 + 0) * FD;
    const float* b1 = bs + (l * 4 + 1) * FD;
    const float* b2 = bs + (l * 4 + 2) * FD;
    const float* b3 = bs + (l * 4 + 3) * FD;

    // r0: drug@W0->hA ; r3: dis@W3->hB ; r1: dis@W1->hC ; r2: drug@W2->hD
    G4 g;
    g.X[0] = xd;  g.W[0] = W0; g.dS[0] = dinvS + 0 * NV; g.H[0] = hA;
    g.X[1] = xs;  g.W[1] = W3; g.dS[1] = dinvS + 3 * NV; g.H[1] = hB;
    g.X[2] = xs;  g.W[2] = W1; g.dS[2] = dinvS + 1 * NV; g.H[2] = hC;
    g.X[3] = xd;  g.W[3] = W2; g.dS[3] = dinvS + 2 * NV; g.H[3] = hD;
    gemm_quad<<<GEMM_GRID, 256, 0, stream>>>(g);

    PullSide pd_;  // drug: A=dd(r0), B=sd(r3)
    pd_.hA = hA; pd_.rpA = rowptr + 0 * (NV + 1); pd_.srcA = srcidx + (size_t)0 * NE;
    pd_.dDA = dinvD + 0 * NV;
    pd_.hB = hB; pd_.rpB = rowptr + 3 * (NV + 1); pd_.srcB = srcidx + (size_t)3 * NE;
    pd_.dDB = dinvD + 3 * NV;
    pd_.bA = b0; pd_.bB = b3; pd_.Y = nextd[l];
    PullSide ps_;  // dis: A=ss(r1), B=ds(r2)
    ps_.hA = hC; ps_.rpA = rowptr + 1 * (NV + 1); ps_.srcA = srcidx + (size_t)1 * NE;
    ps_.dDA = dinvD + 1 * NV;
    ps_.hB = hD; ps_.rpB = rowptr + 2 * (NV + 1); ps_.srcB = srcidx + (size_t)2 * NE;
    ps_.dDB = dinvD + 2 * NV;
    ps_.bA = b1; ps_.bB = b2; ps_.Y = nexts[l];
    pull_dual<<<PULL_GRID, 256, 0, stream>>>(pd_, ps_);

    xd = nextd[l];
    xs = nexts[l];
  }

  linear64<<<LIN_GRID, 256, 0, stream>>>(xd, lw, lb, out);
  linear64<<<LIN_GRID, 256, 0, stream>>>(xs, lw, lb, out + (size_t)NV * NOUT);
}

// Round 10
// 409.437 us; speedup vs baseline: 12.3355x; 1.0611x over previous
//
#include <hip/hip_runtime.h>

#define NV   50000
#define FD   128
#define NE   800000
#define NOUT 64
#define NBIN 196          // ceil(NV/256) coarse buckets of 256 nodes
#define CH   2048         // edges per block in P0/P1
#define NBLK 391          // ceil(NE/CH)
#define SCAN_L (NBIN * NBLK)
#define SCHUNK 2048       // elements per block in hierarchical scan
#define NSCH ((SCAN_L + SCHUNK - 1) / SCHUNK)   // 38
#define CAP2 12288        // LDS staging cap in P2 (avg span ~4083)

typedef unsigned short bf16_t;
typedef unsigned char  u8;
typedef __attribute__((ext_vector_type(8))) short bf16x8;
typedef __attribute__((ext_vector_type(4))) float f32x4;

__device__ __forceinline__ bf16_t f2bf(float f) {
  unsigned u = __builtin_bit_cast(unsigned, f);
  return (bf16_t)((u + 0x7fffu + ((u >> 16) & 1u)) >> 16);
}
__device__ __forceinline__ float bflo(unsigned v) { return __builtin_bit_cast(float, v << 16); }
__device__ __forceinline__ float bfhi(unsigned v) { return __builtin_bit_cast(float, v & 0xffff0000u); }
__device__ __forceinline__ unsigned pk2(float a, float b) {
  return (unsigned)f2bf(a) | ((unsigned)f2bf(b) << 16);
}

struct Ptr4 { const int* p[4]; };

// ================= bucket-sort based CSR build (no global atomics) =================

__global__ __launch_bounds__(256) void p0_hist(Ptr4 rows, Ptr4 cols,
                                               int* __restrict__ blockCnt) {
  const int r = blockIdx.y, blk = blockIdx.x, t = threadIdx.x;
  __shared__ int cd[NBIN], cs[NBIN];
  for (int i = t; i < NBIN; i += 256) { cd[i] = 0; cs[i] = 0; }
  __syncthreads();
  const int e0 = blk * CH;
  const int n4 = min(CH, NE - e0) >> 2;   // counts always divide by 4
  const int4* rw4 = (const int4*)(rows.p[r] + e0);
  const int4* cl4 = (const int4*)(cols.p[r] + e0);
  for (int i = t; i < n4; i += 256) {
    int4 a = cl4[i], b = rw4[i];
    atomicAdd(&cd[a.x >> 8], 1); atomicAdd(&cd[a.y >> 8], 1);
    atomicAdd(&cd[a.z >> 8], 1); atomicAdd(&cd[a.w >> 8], 1);
    atomicAdd(&cs[b.x >> 8], 1); atomicAdd(&cs[b.y >> 8], 1);
    atomicAdd(&cs[b.z >> 8], 1); atomicAdd(&cs[b.w >> 8], 1);
  }
  __syncthreads();
  int* bd = blockCnt + (size_t)(r * 2 + 0) * SCAN_L;
  int* bs = blockCnt + (size_t)(r * 2 + 1) * SCAN_L;
  for (int i = t; i < NBIN; i += 256) {
    bd[i * NBLK + blk] = cd[i];
    bs[i * NBLK + blk] = cs[i];
  }
}

__global__ __launch_bounds__(256) void scan_pass1(const int* __restrict__ blockCnt,
                                                  int* __restrict__ chunkSum) {
  const int r2 = blockIdx.y, chunk = blockIdx.x, t = threadIdx.x;
  const int* a = blockCnt + (size_t)r2 * SCAN_L + chunk * SCHUNK;
  const int n = min(SCHUNK, SCAN_L - chunk * SCHUNK);
  int s = 0;
  for (int i = t; i < n; i += 256) s += a[i];
  __shared__ int sm[256];
  sm[t] = s;
  __syncthreads();
  #pragma unroll
  for (int off = 128; off > 0; off >>= 1) {
    if (t < off) sm[t] += sm[t + off];
    __syncthreads();
  }
  if (t == 0) chunkSum[r2 * NSCH + chunk] = sm[0];
}

__global__ __launch_bounds__(512) void scan_pass2(int* __restrict__ chunkSum,
                                                  int* __restrict__ bucketBase) {
  const int t = threadIdx.x;
  __shared__ int sm[8 * NSCH];
  if (t < 8 * NSCH) sm[t] = chunkSum[t];
  __syncthreads();
  if (t < 8) {
    int run = 0;
    for (int j = 0; j < NSCH; ++j) {
      int v = sm[t * NSCH + j];
      sm[t * NSCH + j] = run;
      run += v;
    }
    bucketBase[t * (NBIN + 1) + NBIN] = NE;
  }
  __syncthreads();
  if (t < 8 * NSCH) chunkSum[t] = sm[t];
}

__global__ __launch_bounds__(256) void scan_pass3(int* __restrict__ blockCnt,
                                                  const int* __restrict__ chunkSum,
                                                  int* __restrict__ bucketBase) {
  const int r2 = blockIdx.y, chunk = blockIdx.x, t = threadIdx.x;
  int* a = blockCnt + (size_t)r2 * SCAN_L + chunk * SCHUNK;
  const int gbase = chunk * SCHUNK;
  const int n = min(SCHUNK, SCAN_L - gbase);
  const int idx0 = t * 8;
  int v[8];
  int s = 0;
  #pragma unroll
  for (int j = 0; j < 8; ++j) {
    int id = idx0 + j;
    v[j] = (id < n) ? a[id] : 0;
    s += v[j];
  }
  __shared__ int sm[256];
  sm[t] = s;
  __syncthreads();
  for (int off = 1; off < 256; off <<= 1) {
    int x = (t >= off) ? sm[t - off] : 0;
    __syncthreads();
    sm[t] += x;
    __syncthreads();
  }
  int pre = ((t == 0) ? 0 : sm[t - 1]) + chunkSum[r2 * NSCH + chunk];
  #pragma unroll
  for (int j = 0; j < 8; ++j) {
    int id = idx0 + j;
    if (id < n) {
      int val = v[j];
      a[id] = pre;
      int g = gbase + id;
      if (g % NBLK == 0) bucketBase[r2 * (NBIN + 1) + g / NBLK] = pre;
      pre += val;
    }
  }
}

// P1: scatter using scanned blockCnt (prefix-diff recovers this block's counts;
// no per-side edge histogram pass needed)
__global__ __launch_bounds__(256) void p1_scatter(Ptr4 rows, Ptr4 cols,
                                                  const int* __restrict__ blockCnt,
                                                  unsigned* __restrict__ pairD,
                                                  u8* __restrict__ srcb) {
  const int r = blockIdx.y, blk = blockIdx.x, t = threadIdx.x;
  const int e0 = blk * CH;
  const int n = min(CH, NE - e0);
  const int* rw = rows.p[r] + e0;
  const int* cl = cols.p[r] + e0;

  __shared__ int sc[256], lofs[256], cnt2[256], baseT[256];
  __shared__ unsigned pr[CH];
  __shared__ u8 binb[CH];
  __shared__ u8 pay8[CH];

  // ---------- dst side ----------
  {
    const int* win = blockCnt + (size_t)(r * 2 + 0) * SCAN_L;
    int c = 0;
    if (t < NBIN) {
      int idx = t * NBLK + blk;
      int base = win[idx];
      int nxt = (idx + 1 < SCAN_L) ? win[idx + 1] : NE;
      baseT[t] = base;
      c = nxt - base;
    }
    sc[t] = c;
    cnt2[t] = 0;
  }
  __syncthreads();
  for (int off = 1; off < 256; off <<= 1) {
    int v = (t >= off) ? sc[t - off] : 0;
    __syncthreads();
    sc[t] += v;
    __syncthreads();
  }
  lofs[t] = (t == 0) ? 0 : sc[t - 1];
  __syncthreads();
  for (int i = t; i < n; i += 256) {
    int c = cl[i];
    int bin = c >> 8;
    int rank = atomicAdd(&cnt2[bin], 1);
    int p = lofs[bin] + rank;
    pr[p] = ((unsigned)(c & 255) << 16) | (unsigned)rw[i];
    binb[p] = (u8)bin;
  }
  __syncthreads();
  {
    unsigned* pd = pairD + (size_t)r * NE;
    for (int i = t; i < n; i += 256) {
      int bin = binb[i];
      pd[baseT[bin] + (i - lofs[bin])] = pr[i];
    }
  }
  __syncthreads();

  // ---------- src side ----------
  {
    const int* win = blockCnt + (size_t)(r * 2 + 1) * SCAN_L;
    int c = 0;
    if (t < NBIN) {
      int idx = t * NBLK + blk;
      int base = win[idx];
      int nxt = (idx + 1 < SCAN_L) ? win[idx + 1] : NE;
      baseT[t] = base;
      c = nxt - base;
    }
    sc[t] = c;
    cnt2[t] = 0;
  }
  __syncthreads();
  for (int off = 1; off < 256; off <<= 1) {
    int v = (t >= off) ? sc[t - off] : 0;
    __syncthreads();
    sc[t] += v;
    __syncthreads();
  }
  lofs[t] = (t == 0) ? 0 : sc[t - 1];
  __syncthreads();
  for (int i = t; i < n; i += 256) {
    int sv = rw[i];
    int bin = sv >> 8;
    int rank = atomicAdd(&cnt2[bin], 1);
    int p = lofs[bin] + rank;
    pay8[p] = (u8)(sv & 255);
    binb[p] = (u8)bin;
  }
  __syncthreads();
  {
    u8* sb = srcb + (size_t)r * NE;
    for (int i = t; i < n; i += 256) {
      int bin = binb[i];
      sb[baseT[bin] + (i - lofs[bin])] = pay8[i];
    }
  }
}

// P2: per dst-bucket -> rowptr, dinvD, and node-sorted srcidx (int32)
__global__ __launch_bounds__(256) void p2_csr(const unsigned* __restrict__ pairD,
                                              const int* __restrict__ bucketBase,
                                              int* __restrict__ srcidx,
                                              int* __restrict__ rowptr,
                                              float* __restrict__ dinvD) {
  const int r = blockIdx.y, bin = blockIdx.x, t = threadIdx.x;
  const int* bb = bucketBase + (r * 2 + 0) * (NBIN + 1);
  const int base = bb[bin], next = bb[bin + 1];
  const int span = next - base;
  const unsigned* pd = pairD + (size_t)r * NE + base;

  __shared__ int cnt[256], sc[256], ex[256], cnt2[256];
  __shared__ int lsrc[CAP2];
  cnt[t] = 0; cnt2[t] = 0;
  __syncthreads();
  for (int i = t; i < span; i += 256) atomicAdd(&cnt[pd[i] >> 16], 1);
  __syncthreads();
  sc[t] = cnt[t];
  __syncthreads();
  for (int off = 1; off < 256; off <<= 1) {
    int v = (t >= off) ? sc[t - off] : 0;
    __syncthreads();
    sc[t] += v;
    __syncthreads();
  }
  ex[t] = (t == 0) ? 0 : sc[t - 1];
  __syncthreads();

  const int node = (bin << 8) + t;
  if (node < NV) {
    rowptr[r * (NV + 1) + node] = base + ex[t];
    float deg = (float)cnt[t];
    dinvD[r * NV + node] = (r < 2) ? rsqrtf(deg + 1.f)
                                   : (deg > 0.f ? rsqrtf(deg) : 0.f);
  }
  if (bin == NBIN - 1 && t == 0) rowptr[r * (NV + 1) + NV] = NE;

  int* so = srcidx + (size_t)r * NE + base;
  if (span <= CAP2) {
    for (int i = t; i < span; i += 256) {
      unsigned v = pd[i];
      int dl = v >> 16;
      int rank = atomicAdd(&cnt2[dl], 1);
      lsrc[ex[dl] + rank] = (int)(v & 0xFFFFu);
    }
    __syncthreads();
    for (int i = t; i < span; i += 256) so[i] = lsrc[i];
  } else {
    for (int i = t; i < span; i += 256) {
      unsigned v = pd[i];
      int dl = v >> 16;
      int rank = atomicAdd(&cnt2[dl], 1);
      so[ex[dl] + rank] = (int)(v & 0xFFFFu);
    }
  }
}

__global__ __launch_bounds__(256) void p2_srcdeg(const u8* __restrict__ srcb,
                                                 const int* __restrict__ bucketBase,
                                                 float* __restrict__ dinvS) {
  const int r = blockIdx.y, bin = blockIdx.x, t = threadIdx.x;
  const int* bb = bucketBase + (r * 2 + 1) * (NBIN + 1);
  const int base = bb[bin], next = bb[bin + 1];
  const int span = next - base;
  const u8* sb = srcb + (size_t)r * NE + base;
  __shared__ int cnt[256];
  cnt[t] = 0;
  __syncthreads();
  for (int i = t; i < span; i += 256) atomicAdd(&cnt[sb[i]], 1);
  __syncthreads();
  int node = (bin << 8) + t;
  if (node < NV) {
    float deg = (float)cnt[t];
    dinvS[r * NV + node] = (r < 2) ? rsqrtf(deg + 1.f)
                                   : (deg > 0.f ? rsqrtf(deg) : 0.f);
  }
}

// ================= W prep: W[8][128k][128n] fp32 -> Wt[8][128n][128k] bf16 =====
__global__ __launch_bounds__(256) void wprep(const float* __restrict__ Wsrc,
                                             bf16_t* __restrict__ Wt) {
  int idx = blockIdx.x * 256 + threadIdx.x;
  if (idx < 8 * 128 * 128) {
    int i = idx >> 14, n = (idx >> 7) & 127, k = idx & 127;
    Wt[idx] = f2bf(Wsrc[(size_t)i * 16384 + k * 128 + n]);
  }
}

// ================= MFMA quad GEMM: H = bf16( dS * (X @ W) ), row-major H ======
// F32IN: X is fp32 (layer 1, reads raw inputs — rounding identical to prior xcvt)
struct G4 {
  const void*   X[4];
  const bf16_t* W[4];
  const float*  dS[4];
  bf16_t*       H[4];
};

template<bool F32IN>
__global__ __launch_bounds__(256) void gemm_quad(G4 g) {
  const int q = blockIdx.y;
  const void* Xb = g.X[q]; const bf16_t* Wt = g.W[q];
  const float* dS = g.dS[q]; bf16_t* H = g.H[q];

  __shared__ bf16_t Xs[128][136];
  __shared__ bf16_t Wsh[128][136];
  __shared__ float sdS[128];
  const int t = threadIdx.x;
  const int row0 = blockIdx.x * 128;

  #pragma unroll
  for (int j = 0; j < 8; ++j) {
    int r = (t >> 4) + j * 16;
    int c = (t & 15) * 8;
    int gr = row0 + r;
    uint4 xv = make_uint4(0u, 0u, 0u, 0u);
    if (gr < NV) {
      if constexpr (F32IN) {
        const float* Xf = (const float*)Xb;
        float4 v0 = *(const float4*)(Xf + (size_t)gr * FD + c);
        float4 v1 = *(const float4*)(Xf + (size_t)gr * FD + c + 4);
        xv = make_uint4(pk2(v0.x, v0.y), pk2(v0.z, v0.w),
                        pk2(v1.x, v1.y), pk2(v1.z, v1.w));
      } else {
        xv = *(const uint4*)((const bf16_t*)Xb + (size_t)gr * FD + c);
      }
    }
    *(uint4*)&Xs[r][c] = xv;
    *(uint4*)&Wsh[r][c] = *(const uint4*)(Wt + (size_t)r * FD + c);
  }
  if (t < 128) {
    int gidx = row0 + t;
    sdS[t] = (gidx < NV) ? dS[gidx] : 0.f;
  }
  __syncthreads();

  const int wave = t >> 6, lane = t & 63;
  const int lr = lane & 15;
  const int lk = (lane >> 4) * 8;
  const int mb = wave * 32;

  f32x4 acc[2][8];
  #pragma unroll
  for (int m = 0; m < 2; ++m)
    #pragma unroll
    for (int n = 0; n < 8; ++n) acc[m][n] = (f32x4){0.f, 0.f, 0.f, 0.f};

  #pragma unroll
  for (int kc = 0; kc < 128; kc += 32) {
    bf16x8 a0 = *(const bf16x8*)&Xs[mb + lr][kc + lk];
    bf16x8 a1 = *(const bf16x8*)&Xs[mb + 16 + lr][kc + lk];
    bf16x8 b[8];
    #pragma unroll
    for (int n = 0; n < 8; ++n) b[n] = *(const bf16x8*)&Wsh[n * 16 + lr][kc + lk];
    #pragma unroll
    for (int n = 0; n < 8; ++n) {
      acc[0][n] = __builtin_amdgcn_mfma_f32_16x16x32_bf16(a0, b[n], acc[0][n], 0, 0, 0);
      acc[1][n] = __builtin_amdgcn_mfma_f32_16x16x32_bf16(a1, b[n], acc[1][n], 0, 0, 0);
    }
  }

  __syncthreads();   // done reading Wsh; reuse as bf16 output staging
  const int rgrp = (lane >> 4) * 4;
  #pragma unroll
  for (int m = 0; m < 2; ++m)
    #pragma unroll
    for (int n = 0; n < 8; ++n)
      #pragma unroll
      for (int j = 0; j < 4; ++j) {
        int rr = mb + m * 16 + rgrp + j;
        Wsh[rr][n * 16 + lr] = f2bf(acc[m][n][j] * sdS[rr]);
      }
  __syncthreads();

  #pragma unroll
  for (int j = 0; j < 8; ++j) {
    int r = (t >> 4) + j * 16;
    int c = (t & 15) * 8;
    int gr = row0 + r;
    if (gr < NV) *(uint4*)(H + (size_t)gr * FD + c) = *(const uint4*)&Wsh[r][c];
  }
}

// ================= fused dual pull aggregation (R7 proven variant) =================
// One wave per node; lane owns 2 dims. Node id / rowptr / indices wave-uniform
// (scalar pipe); row loads 8-deep batched for MLP.
__device__ __forceinline__ void gather8(const bf16_t* __restrict__ h,
                                        const int* __restrict__ src,
                                        int p0, int p1, int d,
                                        float& ax, float& ay) {
  int p = p0;
  while (p + 8 <= p1) {
    int s0 = src[p + 0], s1 = src[p + 1], s2 = src[p + 2], s3 = src[p + 3];
    int s4 = src[p + 4], s5 = src[p + 5], s6 = src[p + 6], s7 = src[p + 7];
    unsigned v0 = *(const unsigned*)(h + (s0 << 7) + d);
    unsigned v1 = *(const unsigned*)(h + (s1 << 7) + d);
    unsigned v2 = *(const unsigned*)(h + (s2 << 7) + d);
    unsigned v3 = *(const unsigned*)(h + (s3 << 7) + d);
    unsigned v4 = *(const unsigned*)(h + (s4 << 7) + d);
    unsigned v5 = *(const unsigned*)(h + (s5 << 7) + d);
    unsigned v6 = *(const unsigned*)(h + (s6 << 7) + d);
    unsigned v7 = *(const unsigned*)(h + (s7 << 7) + d);
    ax += bflo(v0); ay += bfhi(v0);
    ax += bflo(v1); ay += bfhi(v1);
    ax += bflo(v2); ay += bfhi(v2);
    ax += bflo(v3); ay += bfhi(v3);
    ax += bflo(v4); ay += bfhi(v4);
    ax += bflo(v5); ay += bfhi(v5);
    ax += bflo(v6); ay += bfhi(v6);
    ax += bflo(v7); ay += bfhi(v7);
    p += 8;
  }
  while (p + 2 <= p1) {
    int s0 = src[p], s1 = src[p + 1];
    unsigned v0 = *(const unsigned*)(h + (s0 << 7) + d);
    unsigned v1 = *(const unsigned*)(h + (s1 << 7) + d);
    ax += bflo(v0); ay += bfhi(v0);
    ax += bflo(v1); ay += bfhi(v1);
    p += 2;
  }
  if (p < p1) {
    int s = src[p];
    unsigned v = *(const unsigned*)(h + (s << 7) + d);
    ax += bflo(v); ay += bfhi(v);
  }
}

struct PullSide {
  const bf16_t* hA; const int* rpA; const int* srcA; const float* dDA;
  const bf16_t* hB; const int* rpB; const int* srcB; const float* dDB;
  const float* bA; const float* bB; bf16_t* Y;
};

__global__ __launch_bounds__(256) void pull_dual(PullSide s0, PullSide s1) {
  const PullSide& a = blockIdx.y ? s1 : s0;
  const int i = __builtin_amdgcn_readfirstlane(blockIdx.x * 4 + (threadIdx.x >> 6));
  if (i >= NV) return;
  const int lane = threadIdx.x & 63;
  const int d = lane * 2;

  float ax, ay;
  {  // self-loop term (relation A homogeneous; h pre-scaled by dS)
    unsigned v = *(const unsigned*)(a.hA + (i << 7) + d);
    ax = bflo(v); ay = bfhi(v);
  }
  gather8(a.hA, a.srcA, a.rpA[i], a.rpA[i + 1], d, ax, ay);
  float bx = 0.f, by = 0.f;
  gather8(a.hB, a.srcB, a.rpB[i], a.rpB[i + 1], d, bx, by);

  float wA = a.dDA[i], wB = a.dDB[i];
  float ox = fmaf(ax, wA, fmaf(bx, wB, a.bA[d] + a.bB[d]));
  float oy = fmaf(ay, wA, fmaf(by, wB, a.bA[d + 1] + a.bB[d + 1]));
  *(unsigned*)(a.Y + (size_t)i * FD + d) = pk2(fmaxf(ox, 0.f), fmaxf(oy, 0.f));
}

// ================= final linear: Out[NV,64] = X[NV,128] @ lw^T + lb =================
__global__ __launch_bounds__(256) void linear64(const bf16_t* __restrict__ Xb,
                                                const float* __restrict__ lw,
                                                const float* __restrict__ lb,
                                                float* __restrict__ Out) {
  __shared__ float Wt[128][68];
  __shared__ float Xs[64][132];
  const int tid = threadIdx.x;
  const int row0 = blockIdx.x * 64;

  for (int i = tid * 4; i < 64 * 128; i += 1024) {
    float4 v = *(const float4*)(lw + i);
    int o = i >> 7, h = i & 127;
    Wt[h + 0][o] = v.x; Wt[h + 1][o] = v.y; Wt[h + 2][o] = v.z; Wt[h + 3][o] = v.w;
  }
  for (int i = tid * 8; i < 64 * 128; i += 2048) {
    int rr = i >> 7, cc = i & 127;
    int gr = row0 + rr;
    uint4 v = make_uint4(0u, 0u, 0u, 0u);
    if (gr < NV) v = *(const uint4*)(Xb + (size_t)gr * FD + cc);
    unsigned* pv = (unsigned*)&v;
    #pragma unroll
    for (int q = 0; q < 4; ++q) {
      Xs[rr][cc + q * 2]     = bflo(pv[q]);
      Xs[rr][cc + q * 2 + 1] = bfhi(pv[q]);
    }
  }
  __syncthreads();

  const int tx = tid & 15, ty = tid >> 4;
  float acc[4][4];
  #pragma unroll
  for (int i = 0; i < 4; ++i)
    #pragma unroll
    for (int j = 0; j < 4; ++j) acc[i][j] = 0.f;

  for (int k = 0; k < 128; k += 4) {
    float4 xr[4], w[4];
    #pragma unroll
    for (int i = 0; i < 4; ++i) xr[i] = *(const float4*)&Xs[ty * 4 + i][k];
    #pragma unroll
    for (int j = 0; j < 4; ++j) w[j] = *(const float4*)&Wt[k + j][tx * 4];
    #pragma unroll
    for (int i = 0; i < 4; ++i) {
      const float* xv = (const float*)&xr[i];
      #pragma unroll
      for (int j = 0; j < 4; ++j) {
        float x = xv[j];
        acc[i][0] = fmaf(x, w[j].x, acc[i][0]);
        acc[i][1] = fmaf(x, w[j].y, acc[i][1]);
        acc[i][2] = fmaf(x, w[j].z, acc[i][2]);
        acc[i][3] = fmaf(x, w[j].w, acc[i][3]);
      }
    }
  }
  float4 bias = *(const float4*)(lb + tx * 4);
  #pragma unroll
  for (int i = 0; i < 4; ++i) {
    int gr = row0 + ty * 4 + i;
    if (gr < NV) {
      *(float4*)(Out + (size_t)gr * NOUT + tx * 4) =
          make_float4(acc[i][0] + bias.x, acc[i][1] + bias.y,
                      acc[i][2] + bias.z, acc[i][3] + bias.w);
    }
  }
}

// ================= host orchestration =================

extern "C" void kernel_launch(void* const* d_in, const int* in_sizes, int n_in,
                              void* d_out, int out_size, void* d_ws, size_t ws_size,
                              hipStream_t stream) {
  const float* x_drug = (const float*)d_in[0];
  const float* x_dis  = (const float*)d_in[1];
  const int* ei[4] = { (const int*)d_in[2], (const int*)d_in[3],
                       (const int*)d_in[4], (const int*)d_in[5] };  // dd, ss, ds, sd
  const float* Ws = (const float*)d_in[6];
  const float* bs = (const float*)d_in[7];
  const float* lw = (const float*)d_in[8];
  const float* lb = (const float*)d_in[9];
  float* out = (float*)d_out;

  char* p = (char*)d_ws;
  auto take = [&](size_t bytes) -> void* {
    char* q = p;
    p += (bytes + 255) & ~(size_t)255;
    return (void*)q;
  };
  int* blockCnt   = (int*)take((size_t)8 * SCAN_L * sizeof(int));
  int* chunkSum   = (int*)take((size_t)8 * NSCH * sizeof(int));
  int* bucketBase = (int*)take((size_t)8 * (NBIN + 1) * sizeof(int));
  unsigned* pairD = (unsigned*)take((size_t)4 * NE * sizeof(unsigned));
  u8* srcb        = (u8*)take((size_t)4 * NE);
  int* srcidx     = (int*)take((size_t)4 * NE * sizeof(int));
  int* rowptr     = (int*)take((size_t)4 * (NV + 1) * sizeof(int));
  float* dinvS    = (float*)take((size_t)4 * NV * sizeof(float));
  float* dinvD    = (float*)take((size_t)4 * NV * sizeof(float));
  bf16_t* hA  = (bf16_t*)take((size_t)NV * FD * sizeof(bf16_t));
  bf16_t* hB  = (bf16_t*)take((size_t)NV * FD * sizeof(bf16_t));
  bf16_t* hC  = (bf16_t*)take((size_t)NV * FD * sizeof(bf16_t));
  bf16_t* hD  = (bf16_t*)take((size_t)NV * FD * sizeof(bf16_t));
  bf16_t* Wtb = (bf16_t*)take((size_t)8 * FD * FD * sizeof(bf16_t));
  bf16_t* XD1 = (bf16_t*)take((size_t)NV * FD * sizeof(bf16_t));
  bf16_t* XS1 = (bf16_t*)take((size_t)NV * FD * sizeof(bf16_t));
  bf16_t* XD2 = (bf16_t*)take((size_t)NV * FD * sizeof(bf16_t));
  bf16_t* XS2 = (bf16_t*)take((size_t)NV * FD * sizeof(bf16_t));

  Ptr4 rows = {{ ei[0], ei[1], ei[2], ei[3] }};
  Ptr4 cols = {{ ei[0] + NE, ei[1] + NE, ei[2] + NE, ei[3] + NE }};

  // ---- prep ----
  p0_hist<<<dim3(NBLK, 4), 256, 0, stream>>>(rows, cols, blockCnt);
  scan_pass1<<<dim3(NSCH, 8), 256, 0, stream>>>(blockCnt, chunkSum);
  scan_pass2<<<1, 512, 0, stream>>>(chunkSum, bucketBase);
  scan_pass3<<<dim3(NSCH, 8), 256, 0, stream>>>(blockCnt, chunkSum, bucketBase);
  p1_scatter<<<dim3(NBLK, 4), 256, 0, stream>>>(rows, cols, blockCnt, pairD, srcb);
  p2_csr<<<dim3(NBIN, 4), 256, 0, stream>>>(pairD, bucketBase, srcidx, rowptr, dinvD);
  p2_srcdeg<<<dim3(NBIN, 4), 256, 0, stream>>>(srcb, bucketBase, dinvS);
  wprep<<<(8 * FD * FD + 255) / 256, 256, 0, stream>>>(Ws, Wtb);

  // ---- layers ----
  const dim3 GEMM_GRID((NV + 127) / 128, 4);   // 391 x 4
  const dim3 PULL_GRID((NV + 3) / 4, 2);       // 12500 x 2
  const int LIN_GRID = (NV + 63) / 64;
  const void* xd = x_drug;    // layer 1: fp32 inputs
  const void* xs = x_dis;
  bf16_t* nextd[2] = {XD1, XD2};
  bf16_t* nexts[2] = {XS1, XS2};
  for (int l = 0; l < 2; ++l) {
    const bf16_t* W0 = Wtb + (size_t)(l * 4 + 0) * FD * FD;
    const bf16_t* W1 = Wtb + (size_t)(l * 4 + 1) * FD * FD;
    const bf16_t* W2 = Wtb + (size_t)(l * 4 + 2) * FD * FD;
    const bf16_t* W3 = Wtb + (size_t)(l * 4 + 3) * FD * FD;
    const float* b0 = bs + (l * 4 + 0) * FD;
    const float* b1 = bs + (l * 4 + 1) * FD;
    const float* b2 = bs + (l * 4 + 2) * FD;
    const float* b3 = bs + (l * 4 + 3) * FD;

    // r0: drug@W0->hA ; r3: dis@W3->hB ; r1: dis@W1->hC ; r2: drug@W2->hD
    G4 g;
    g.X[0] = xd;  g.W[0] = W0; g.dS[0] = dinvS + 0 * NV; g.H[0] = hA;
    g.X[1] = xs;  g.W[1] = W3; g.dS[1] = dinvS + 3 * NV; g.H[1] = hB;
    g.X[2] = xs;  g.W[2] = W1; g.dS[2] = dinvS + 1 * NV; g.H[2] = hC;
    g.X[3] = xd;  g.W[3] = W2; g.dS[3] = dinvS + 2 * NV; g.H[3] = hD;
    if (l == 0) gemm_quad<true><<<GEMM_GRID, 256, 0, stream>>>(g);
    else        gemm_quad<false><<<GEMM_GRID, 256, 0, stream>>>(g);

    PullSide pd_;  // drug: A=dd(r0), B=sd(r3)
    pd_.hA = hA; pd_.rpA = rowptr + 0 * (NV + 1); pd_.srcA = srcidx + (size_t)0 * NE;
    pd_.dDA = dinvD + 0 * NV;
    pd_.hB = hB; pd_.rpB = rowptr + 3 * (NV + 1); pd_.srcB = srcidx + (size_t)3 * NE;
    pd_.dDB = dinvD + 3 * NV;
    pd_.bA = b0; pd_.bB = b3; pd_.Y = nextd[l];
    PullSide ps_;  // dis: A=ss(r1), B=ds(r2)
    ps_.hA = hC; ps_.rpA = rowptr + 1 * (NV + 1); ps_.srcA = srcidx + (size_t)1 * NE;
    ps_.dDA = dinvD + 1 * NV;
    ps_.hB = hD; ps_.rpB = rowptr + 2 * (NV + 1); ps_.srcB = srcidx + (size_t)2 * NE;
    ps_.dDB = dinvD + 2 * NV;
    ps_.bA = b1; ps_.bB = b2; ps_.Y = nexts[l];
    pull_dual<<<PULL_GRID, 256, 0, stream>>>(pd_, ps_);

    xd = nextd[l];
    xs = nexts[l];
  }

  linear64<<<LIN_GRID, 256, 0, stream>>>((const bf16_t*)xd, lw, lb, out);
  linear64<<<LIN_GRID, 256, 0, stream>>>((const bf16_t*)xs, lw, lb, out + (size_t)NV * NOUT);
}

// Round 11
// 408.574 us; speedup vs baseline: 12.3616x; 1.0021x over previous
//
#include <hip/hip_runtime.h>

#define NV   50000
#define FD   128
#define NE   800000
#define NOUT 64
#define NBIN 196          // ceil(NV/256) coarse buckets of 256 nodes
#define CH   2048         // edges per block in P0/P1
#define NBLK 391          // ceil(NE/CH)
#define SCAN_L (NBIN * NBLK)
#define SCHUNK 2048       // elements per block in hierarchical scan
#define NSCH ((SCAN_L + SCHUNK - 1) / SCHUNK)   // 38
#define CAP2 12288        // LDS staging cap in P2 (avg span ~4083)

typedef unsigned short bf16_t;
typedef unsigned char  u8;
typedef __attribute__((ext_vector_type(8))) short bf16x8;
typedef __attribute__((ext_vector_type(4))) float f32x4;

__device__ __forceinline__ bf16_t f2bf(float f) {
  unsigned u = __builtin_bit_cast(unsigned, f);
  return (bf16_t)((u + 0x7fffu + ((u >> 16) & 1u)) >> 16);
}
__device__ __forceinline__ float bflo(unsigned v) { return __builtin_bit_cast(float, v << 16); }
__device__ __forceinline__ float bfhi(unsigned v) { return __builtin_bit_cast(float, v & 0xffff0000u); }
__device__ __forceinline__ unsigned pk2(float a, float b) {
  return (unsigned)f2bf(a) | ((unsigned)f2bf(b) << 16);
}

struct Ptr4 { const int* p[4]; };

// ================= bucket-sort based CSR build (no global atomics) =================

__global__ __launch_bounds__(256) void p0_hist(Ptr4 rows, Ptr4 cols,
                                               int* __restrict__ blockCnt) {
  const int r = blockIdx.y, blk = blockIdx.x, t = threadIdx.x;
  __shared__ int cd[NBIN], cs[NBIN];
  for (int i = t; i < NBIN; i += 256) { cd[i] = 0; cs[i] = 0; }
  __syncthreads();
  const int e0 = blk * CH;
  const int n4 = min(CH, NE - e0) >> 2;   // counts always divide by 4
  const int4* rw4 = (const int4*)(rows.p[r] + e0);
  const int4* cl4 = (const int4*)(cols.p[r] + e0);
  for (int i = t; i < n4; i += 256) {
    int4 a = cl4[i], b = rw4[i];
    atomicAdd(&cd[a.x >> 8], 1); atomicAdd(&cd[a.y >> 8], 1);
    atomicAdd(&cd[a.z >> 8], 1); atomicAdd(&cd[a.w >> 8], 1);
    atomicAdd(&cs[b.x >> 8], 1); atomicAdd(&cs[b.y >> 8], 1);
    atomicAdd(&cs[b.z >> 8], 1); atomicAdd(&cs[b.w >> 8], 1);
  }
  __syncthreads();
  int* bd = blockCnt + (size_t)(r * 2 + 0) * SCAN_L;
  int* bs = blockCnt + (size_t)(r * 2 + 1) * SCAN_L;
  for (int i = t; i < NBIN; i += 256) {
    bd[i * NBLK + blk] = cd[i];
    bs[i * NBLK + blk] = cs[i];
  }
}

__global__ __launch_bounds__(256) void scan_pass1(const int* __restrict__ blockCnt,
                                                  int* __restrict__ chunkSum) {
  const int r2 = blockIdx.y, chunk = blockIdx.x, t = threadIdx.x;
  const int* a = blockCnt + (size_t)r2 * SCAN_L + chunk * SCHUNK;
  const int n = min(SCHUNK, SCAN_L - chunk * SCHUNK);
  int s = 0;
  for (int i = t; i < n; i += 256) s += a[i];
  __shared__ int sm[256];
  sm[t] = s;
  __syncthreads();
  #pragma unroll
  for (int off = 128; off > 0; off >>= 1) {
    if (t < off) sm[t] += sm[t + off];
    __syncthreads();
  }
  if (t == 0) chunkSum[r2 * NSCH + chunk] = sm[0];
}

__global__ __launch_bounds__(512) void scan_pass2(int* __restrict__ chunkSum,
                                                  int* __restrict__ bucketBase) {
  const int t = threadIdx.x;
  __shared__ int sm[8 * NSCH];
  if (t < 8 * NSCH) sm[t] = chunkSum[t];
  __syncthreads();
  if (t < 8) {
    int run = 0;
    for (int j = 0; j < NSCH; ++j) {
      int v = sm[t * NSCH + j];
      sm[t * NSCH + j] = run;
      run += v;
    }
    bucketBase[t * (NBIN + 1) + NBIN] = NE;
  }
  __syncthreads();
  if (t < 8 * NSCH) chunkSum[t] = sm[t];
}

__global__ __launch_bounds__(256) void scan_pass3(int* __restrict__ blockCnt,
                                                  const int* __restrict__ chunkSum,
                                                  int* __restrict__ bucketBase) {
  const int r2 = blockIdx.y, chunk = blockIdx.x, t = threadIdx.x;
  int* a = blockCnt + (size_t)r2 * SCAN_L + chunk * SCHUNK;
  const int gbase = chunk * SCHUNK;
  const int n = min(SCHUNK, SCAN_L - gbase);
  const int idx0 = t * 8;
  int v[8];
  int s = 0;
  #pragma unroll
  for (int j = 0; j < 8; ++j) {
    int id = idx0 + j;
    v[j] = (id < n) ? a[id] : 0;
    s += v[j];
  }
  __shared__ int sm[256];
  sm[t] = s;
  __syncthreads();
  for (int off = 1; off < 256; off <<= 1) {
    int x = (t >= off) ? sm[t - off] : 0;
    __syncthreads();
    sm[t] += x;
    __syncthreads();
  }
  int pre = ((t == 0) ? 0 : sm[t - 1]) + chunkSum[r2 * NSCH + chunk];
  #pragma unroll
  for (int j = 0; j < 8; ++j) {
    int id = idx0 + j;
    if (id < n) {
      int val = v[j];
      a[id] = pre;
      int g = gbase + id;
      if (g % NBLK == 0) bucketBase[r2 * (NBIN + 1) + g / NBLK] = pre;
      pre += val;
    }
  }
}

// P1: scatter using scanned blockCnt (prefix-diff recovers this block's counts)
__global__ __launch_bounds__(256) void p1_scatter(Ptr4 rows, Ptr4 cols,
                                                  const int* __restrict__ blockCnt,
                                                  unsigned* __restrict__ pairD,
                                                  u8* __restrict__ srcb) {
  const int r = blockIdx.y, blk = blockIdx.x, t = threadIdx.x;
  const int e0 = blk * CH;
  const int n = min(CH, NE - e0);
  const int* rw = rows.p[r] + e0;
  const int* cl = cols.p[r] + e0;

  __shared__ int sc[256], lofs[256], cnt2[256], baseT[256];
  __shared__ unsigned pr[CH];
  __shared__ u8 binb[CH];
  __shared__ u8 pay8[CH];

  // ---------- dst side ----------
  {
    const int* win = blockCnt + (size_t)(r * 2 + 0) * SCAN_L;
    int c = 0;
    if (t < NBIN) {
      int idx = t * NBLK + blk;
      int base = win[idx];
      int nxt = (idx + 1 < SCAN_L) ? win[idx + 1] : NE;
      baseT[t] = base;
      c = nxt - base;
    }
    sc[t] = c;
    cnt2[t] = 0;
  }
  __syncthreads();
  for (int off = 1; off < 256; off <<= 1) {
    int v = (t >= off) ? sc[t - off] : 0;
    __syncthreads();
    sc[t] += v;
    __syncthreads();
  }
  lofs[t] = (t == 0) ? 0 : sc[t - 1];
  __syncthreads();
  for (int i = t; i < n; i += 256) {
    int c = cl[i];
    int bin = c >> 8;
    int rank = atomicAdd(&cnt2[bin], 1);
    int p = lofs[bin] + rank;
    pr[p] = ((unsigned)(c & 255) << 16) | (unsigned)rw[i];
    binb[p] = (u8)bin;
  }
  __syncthreads();
  {
    unsigned* pd = pairD + (size_t)r * NE;
    for (int i = t; i < n; i += 256) {
      int bin = binb[i];
      pd[baseT[bin] + (i - lofs[bin])] = pr[i];
    }
  }
  __syncthreads();

  // ---------- src side ----------
  {
    const int* win = blockCnt + (size_t)(r * 2 + 1) * SCAN_L;
    int c = 0;
    if (t < NBIN) {
      int idx = t * NBLK + blk;
      int base = win[idx];
      int nxt = (idx + 1 < SCAN_L) ? win[idx + 1] : NE;
      baseT[t] = base;
      c = nxt - base;
    }
    sc[t] = c;
    cnt2[t] = 0;
  }
  __syncthreads();
  for (int off = 1; off < 256; off <<= 1) {
    int v = (t >= off) ? sc[t - off] : 0;
    __syncthreads();
    sc[t] += v;
    __syncthreads();
  }
  lofs[t] = (t == 0) ? 0 : sc[t - 1];
  __syncthreads();
  for (int i = t; i < n; i += 256) {
    int sv = rw[i];
    int bin = sv >> 8;
    int rank = atomicAdd(&cnt2[bin], 1);
    int p = lofs[bin] + rank;
    pay8[p] = (u8)(sv & 255);
    binb[p] = (u8)bin;
  }
  __syncthreads();
  {
    u8* sb = srcb + (size_t)r * NE;
    for (int i = t; i < n; i += 256) {
      int bin = binb[i];
      sb[baseT[bin] + (i - lofs[bin])] = pay8[i];
    }
  }
}

// P2 merged: per bucket -> rowptr, dinvD, node-sorted srcidx (int32), AND dinvS
__global__ __launch_bounds__(256) void p2_build(const unsigned* __restrict__ pairD,
                                                const u8* __restrict__ srcb,
                                                const int* __restrict__ bucketBase,
                                                int* __restrict__ srcidx,
                                                int* __restrict__ rowptr,
                                                float* __restrict__ dinvD,
                                                float* __restrict__ dinvS) {
  const int r = blockIdx.y, bin = blockIdx.x, t = threadIdx.x;
  __shared__ int cnt[256], sc[256], ex[256], cnt2[256];
  __shared__ int lsrc[CAP2];

  // ---- dst-side CSR ----
  {
    const int* bb = bucketBase + (r * 2 + 0) * (NBIN + 1);
    const int base = bb[bin], next = bb[bin + 1];
    const int span = next - base;
    const unsigned* pd = pairD + (size_t)r * NE + base;

    cnt[t] = 0; cnt2[t] = 0;
    __syncthreads();
    for (int i = t; i < span; i += 256) atomicAdd(&cnt[pd[i] >> 16], 1);
    __syncthreads();
    sc[t] = cnt[t];
    __syncthreads();
    for (int off = 1; off < 256; off <<= 1) {
      int v = (t >= off) ? sc[t - off] : 0;
      __syncthreads();
      sc[t] += v;
      __syncthreads();
    }
    ex[t] = (t == 0) ? 0 : sc[t - 1];
    __syncthreads();

    const int node = (bin << 8) + t;
    if (node < NV) {
      rowptr[r * (NV + 1) + node] = base + ex[t];
      float deg = (float)cnt[t];
      dinvD[r * NV + node] = (r < 2) ? rsqrtf(deg + 1.f)
                                     : (deg > 0.f ? rsqrtf(deg) : 0.f);
    }
    if (bin == NBIN - 1 && t == 0) rowptr[r * (NV + 1) + NV] = NE;

    int* so = srcidx + (size_t)r * NE + base;
    if (span <= CAP2) {
      for (int i = t; i < span; i += 256) {
        unsigned v = pd[i];
        int dl = v >> 16;
        int rank = atomicAdd(&cnt2[dl], 1);
        lsrc[ex[dl] + rank] = (int)(v & 0xFFFFu);
      }
      __syncthreads();
      for (int i = t; i < span; i += 256) so[i] = lsrc[i];
    } else {
      for (int i = t; i < span; i += 256) {
        unsigned v = pd[i];
        int dl = v >> 16;
        int rank = atomicAdd(&cnt2[dl], 1);
        so[ex[dl] + rank] = (int)(v & 0xFFFFu);
      }
    }
  }
  __syncthreads();

  // ---- src-side degrees ----
  {
    const int* bb = bucketBase + (r * 2 + 1) * (NBIN + 1);
    const int base = bb[bin], next = bb[bin + 1];
    const int span = next - base;
    const u8* sb = srcb + (size_t)r * NE + base;
    cnt[t] = 0;
    __syncthreads();
    for (int i = t; i < span; i += 256) atomicAdd(&cnt[sb[i]], 1);
    __syncthreads();
    int node = (bin << 8) + t;
    if (node < NV) {
      float deg = (float)cnt[t];
      dinvS[r * NV + node] = (r < 2) ? rsqrtf(deg + 1.f)
                                     : (deg > 0.f ? rsqrtf(deg) : 0.f);
    }
  }
}

// ================= W prep: W[8][128k][128n] fp32 -> Wt[8][128n][128k] bf16 =====
__global__ __launch_bounds__(256) void wprep(const float* __restrict__ Wsrc,
                                             bf16_t* __restrict__ Wt) {
  int idx = blockIdx.x * 256 + threadIdx.x;
  if (idx < 8 * 128 * 128) {
    int i = idx >> 14, n = (idx >> 7) & 127, k = idx & 127;
    Wt[idx] = f2bf(Wsrc[(size_t)i * 16384 + k * 128 + n]);
  }
}

// ================= MFMA share-X pair GEMM: Ha=bf16(dSa*(X@Wa)), Hb=bf16(dSb*(X@Wb))
// X staged once per block; two sequential MFMA passes reuse the same accumulators.
struct G2 {
  const void*   X;
  const bf16_t* Wa; const float* dSa; bf16_t* Ha;
  const bf16_t* Wb; const float* dSb; bf16_t* Hb;
};

template<bool F32IN>
__global__ __launch_bounds__(256) void gemm_pairX(G2 g0, G2 g1) {
  const G2& g = blockIdx.y ? g1 : g0;

  __shared__ bf16_t Xs[128][136];
  __shared__ bf16_t Wsh[2][128][136];
  __shared__ float sdS[2][128];
  const int t = threadIdx.x;
  const int row0 = blockIdx.x * 128;

  #pragma unroll
  for (int j = 0; j < 8; ++j) {
    int r = (t >> 4) + j * 16;
    int c = (t & 15) * 8;
    int gr = row0 + r;
    uint4 xv = make_uint4(0u, 0u, 0u, 0u);
    if (gr < NV) {
      if constexpr (F32IN) {
        const float* Xf = (const float*)g.X;
        float4 v0 = *(const float4*)(Xf + (size_t)gr * FD + c);
        float4 v1 = *(const float4*)(Xf + (size_t)gr * FD + c + 4);
        xv = make_uint4(pk2(v0.x, v0.y), pk2(v0.z, v0.w),
                        pk2(v1.x, v1.y), pk2(v1.z, v1.w));
      } else {
        xv = *(const uint4*)((const bf16_t*)g.X + (size_t)gr * FD + c);
      }
    }
    *(uint4*)&Xs[r][c] = xv;
    *(uint4*)&Wsh[0][r][c] = *(const uint4*)(g.Wa + (size_t)r * FD + c);
    *(uint4*)&Wsh[1][r][c] = *(const uint4*)(g.Wb + (size_t)r * FD + c);
  }
  if (t < 128) {
    int gidx = row0 + t;
    sdS[0][t] = (gidx < NV) ? g.dSa[gidx] : 0.f;
    sdS[1][t] = (gidx < NV) ? g.dSb[gidx] : 0.f;
  }
  __syncthreads();

  const int wave = t >> 6, lane = t & 63;
  const int lr = lane & 15;
  const int lk = (lane >> 4) * 8;
  const int mb = wave * 32;
  const int rgrp = (lane >> 4) * 4;

  #pragma unroll
  for (int s = 0; s < 2; ++s) {
    f32x4 acc[2][8];
    #pragma unroll
    for (int m = 0; m < 2; ++m)
      #pragma unroll
      for (int n = 0; n < 8; ++n) acc[m][n] = (f32x4){0.f, 0.f, 0.f, 0.f};

    #pragma unroll
    for (int kc = 0; kc < 128; kc += 32) {
      bf16x8 a0 = *(const bf16x8*)&Xs[mb + lr][kc + lk];
      bf16x8 a1 = *(const bf16x8*)&Xs[mb + 16 + lr][kc + lk];
      bf16x8 b[8];
      #pragma unroll
      for (int n = 0; n < 8; ++n) b[n] = *(const bf16x8*)&Wsh[s][n * 16 + lr][kc + lk];
      #pragma unroll
      for (int n = 0; n < 8; ++n) {
        acc[0][n] = __builtin_amdgcn_mfma_f32_16x16x32_bf16(a0, b[n], acc[0][n], 0, 0, 0);
        acc[1][n] = __builtin_amdgcn_mfma_f32_16x16x32_bf16(a1, b[n], acc[1][n], 0, 0, 0);
      }
    }

    __syncthreads();   // all reads of Wsh[s] done; reuse as output staging
    #pragma unroll
    for (int m = 0; m < 2; ++m)
      #pragma unroll
      for (int n = 0; n < 8; ++n)
        #pragma unroll
        for (int j = 0; j < 4; ++j) {
          int rr = mb + m * 16 + rgrp + j;
          Wsh[s][rr][n * 16 + lr] = f2bf(acc[m][n][j] * sdS[s][rr]);
        }
    __syncthreads();

    bf16_t* H = s ? g.Hb : g.Ha;
    #pragma unroll
    for (int j = 0; j < 8; ++j) {
      int r = (t >> 4) + j * 16;
      int c = (t & 15) * 8;
      int gr = row0 + r;
      if (gr < NV) *(uint4*)(H + (size_t)gr * FD + c) = *(const uint4*)&Wsh[s][r][c];
    }
    // next pass reads Xs and Wsh[1] only; no barrier needed (store reads Wsh[s])
  }
}

// ================= fused dual pull aggregation (R7 proven variant, untouched) =====
__device__ __forceinline__ void gather8(const bf16_t* __restrict__ h,
                                        const int* __restrict__ src,
                                        int p0, int p1, int d,
                                        float& ax, float& ay) {
  int p = p0;
  while (p + 8 <= p1) {
    int s0 = src[p + 0], s1 = src[p + 1], s2 = src[p + 2], s3 = src[p + 3];
    int s4 = src[p + 4], s5 = src[p + 5], s6 = src[p + 6], s7 = src[p + 7];
    unsigned v0 = *(const unsigned*)(h + (s0 << 7) + d);
    unsigned v1 = *(const unsigned*)(h + (s1 << 7) + d);
    unsigned v2 = *(const unsigned*)(h + (s2 << 7) + d);
    unsigned v3 = *(const unsigned*)(h + (s3 << 7) + d);
    unsigned v4 = *(const unsigned*)(h + (s4 << 7) + d);
    unsigned v5 = *(const unsigned*)(h + (s5 << 7) + d);
    unsigned v6 = *(const unsigned*)(h + (s6 << 7) + d);
    unsigned v7 = *(const unsigned*)(h + (s7 << 7) + d);
    ax += bflo(v0); ay += bfhi(v0);
    ax += bflo(v1); ay += bfhi(v1);
    ax += bflo(v2); ay += bfhi(v2);
    ax += bflo(v3); ay += bfhi(v3);
    ax += bflo(v4); ay += bfhi(v4);
    ax += bflo(v5); ay += bfhi(v5);
    ax += bflo(v6); ay += bfhi(v6);
    ax += bflo(v7); ay += bfhi(v7);
    p += 8;
  }
  while (p + 2 <= p1) {
    int s0 = src[p], s1 = src[p + 1];
    unsigned v0 = *(const unsigned*)(h + (s0 << 7) + d);
    unsigned v1 = *(const unsigned*)(h + (s1 << 7) + d);
    ax += bflo(v0); ay += bfhi(v0);
    ax += bflo(v1); ay += bfhi(v1);
    p += 2;
  }
  if (p < p1) {
    int s = src[p];
    unsigned v = *(const unsigned*)(h + (s << 7) + d);
    ax += bflo(v); ay += bfhi(v);
  }
}

struct PullSide {
  const bf16_t* hA; const int* rpA; const int* srcA; const float* dDA;
  const bf16_t* hB; const int* rpB; const int* srcB; const float* dDB;
  const float* bA; const float* bB; bf16_t* Y;
};

__global__ __launch_bounds__(256) void pull_dual(PullSide s0, PullSide s1) {
  const PullSide& a = blockIdx.y ? s1 : s0;
  const int i = __builtin_amdgcn_readfirstlane(blockIdx.x * 4 + (threadIdx.x >> 6));
  if (i >= NV) return;
  const int lane = threadIdx.x & 63;
  const int d = lane * 2;

  float ax, ay;
  {  // self-loop term (relation A homogeneous; h pre-scaled by dS)
    unsigned v = *(const unsigned*)(a.hA + (i << 7) + d);
    ax = bflo(v); ay = bfhi(v);
  }
  gather8(a.hA, a.srcA, a.rpA[i], a.rpA[i + 1], d, ax, ay);
  float bx = 0.f, by = 0.f;
  gather8(a.hB, a.srcB, a.rpB[i], a.rpB[i + 1], d, bx, by);

  float wA = a.dDA[i], wB = a.dDB[i];
  float ox = fmaf(ax, wA, fmaf(bx, wB, a.bA[d] + a.bB[d]));
  float oy = fmaf(ay, wA, fmaf(by, wB, a.bA[d + 1] + a.bB[d + 1]));
  *(unsigned*)(a.Y + (size_t)i * FD + d) = pk2(fmaxf(ox, 0.f), fmaxf(oy, 0.f));
}

// ================= final linear (both types in one dispatch) =================
__global__ __launch_bounds__(256) void linear64(const bf16_t* __restrict__ X0,
                                                const bf16_t* __restrict__ X1,
                                                const float* __restrict__ lw,
                                                const float* __restrict__ lb,
                                                float* __restrict__ Out) {
  const bf16_t* Xb = blockIdx.y ? X1 : X0;
  float* O = Out + (size_t)blockIdx.y * NV * NOUT;
  __shared__ float Wt[128][68];
  __shared__ float Xs[64][132];
  const int tid = threadIdx.x;
  const int row0 = blockIdx.x * 64;

  for (int i = tid * 4; i < 64 * 128; i += 1024) {
    float4 v = *(const float4*)(lw + i);
    int o = i >> 7, h = i & 127;
    Wt[h + 0][o] = v.x; Wt[h + 1][o] = v.y; Wt[h + 2][o] = v.z; Wt[h + 3][o] = v.w;
  }
  for (int i = tid * 8; i < 64 * 128; i += 2048) {
    int rr = i >> 7, cc = i & 127;
    int gr = row0 + rr;
    uint4 v = make_uint4(0u, 0u, 0u, 0u);
    if (gr < NV) v = *(const uint4*)(Xb + (size_t)gr * FD + cc);
    unsigned* pv = (unsigned*)&v;
    #pragma unroll
    for (int q = 0; q < 4; ++q) {
      Xs[rr][cc + q * 2]     = bflo(pv[q]);
      Xs[rr][cc + q * 2 + 1] = bfhi(pv[q]);
    }
  }
  __syncthreads();

  const int tx = tid & 15, ty = tid >> 4;
  float acc[4][4];
  #pragma unroll
  for (int i = 0; i < 4; ++i)
    #pragma unroll
    for (int j = 0; j < 4; ++j) acc[i][j] = 0.f;

  for (int k = 0; k < 128; k += 4) {
    float4 xr[4], w[4];
    #pragma unroll
    for (int i = 0; i < 4; ++i) xr[i] = *(const float4*)&Xs[ty * 4 + i][k];
    #pragma unroll
    for (int j = 0; j < 4; ++j) w[j] = *(const float4*)&Wt[k + j][tx * 4];
    #pragma unroll
    for (int i = 0; i < 4; ++i) {
      const float* xv = (const float*)&xr[i];
      #pragma unroll
      for (int j = 0; j < 4; ++j) {
        float x = xv[j];
        acc[i][0] = fmaf(x, w[j].x, acc[i][0]);
        acc[i][1] = fmaf(x, w[j].y, acc[i][1]);
        acc[i][2] = fmaf(x, w[j].z, acc[i][2]);
        acc[i][3] = fmaf(x, w[j].w, acc[i][3]);
      }
    }
  }
  float4 bias = *(const float4*)(lb + tx * 4);
  #pragma unroll
  for (int i = 0; i < 4; ++i) {
    int gr = row0 + ty * 4 + i;
    if (gr < NV) {
      *(float4*)(O + (size_t)gr * NOUT + tx * 4) =
          make_float4(acc[i][0] + bias.x, acc[i][1] + bias.y,
                      acc[i][2] + bias.z, acc[i][3] + bias.w);
    }
  }
}

// ================= host orchestration =================

extern "C" void kernel_launch(void* const* d_in, const int* in_sizes, int n_in,
                              void* d_out, int out_size, void* d_ws, size_t ws_size,
                              hipStream_t stream) {
  const float* x_drug = (const float*)d_in[0];
  const float* x_dis  = (const float*)d_in[1];
  const int* ei[4] = { (const int*)d_in[2], (const int*)d_in[3],
                       (const int*)d_in[4], (const int*)d_in[5] };  // dd, ss, ds, sd
  const float* Ws = (const float*)d_in[6];
  const float* bs = (const float*)d_in[7];
  const float* lw = (const float*)d_in[8];
  const float* lb = (const float*)d_in[9];
  float* out = (float*)d_out;

  char* p = (char*)d_ws;
  auto take = [&](size_t bytes) -> void* {
    char* q = p;
    p += (bytes + 255) & ~(size_t)255;
    return (void*)q;
  };
  int* blockCnt   = (int*)take((size_t)8 * SCAN_L * sizeof(int));
  int* chunkSum   = (int*)take((size_t)8 * NSCH * sizeof(int));
  int* bucketBase = (int*)take((size_t)8 * (NBIN + 1) * sizeof(int));
  unsigned* pairD = (unsigned*)take((size_t)4 * NE * sizeof(unsigned));
  u8* srcb        = (u8*)take((size_t)4 * NE);
  int* srcidx     = (int*)take((size_t)4 * NE * sizeof(int));
  int* rowptr     = (int*)take((size_t)4 * (NV + 1) * sizeof(int));
  float* dinvS    = (float*)take((size_t)4 * NV * sizeof(float));
  float* dinvD    = (float*)take((size_t)4 * NV * sizeof(float));
  bf16_t* hA  = (bf16_t*)take((size_t)NV * FD * sizeof(bf16_t));
  bf16_t* hB  = (bf16_t*)take((size_t)NV * FD * sizeof(bf16_t));
  bf16_t* hC  = (bf16_t*)take((size_t)NV * FD * sizeof(bf16_t));
  bf16_t* hD  = (bf16_t*)take((size_t)NV * FD * sizeof(bf16_t));
  bf16_t* Wtb = (bf16_t*)take((size_t)8 * FD * FD * sizeof(bf16_t));
  bf16_t* XD1 = (bf16_t*)take((size_t)NV * FD * sizeof(bf16_t));
  bf16_t* XS1 = (bf16_t*)take((size_t)NV * FD * sizeof(bf16_t));
  bf16_t* XD2 = (bf16_t*)take((size_t)NV * FD * sizeof(bf16_t));
  bf16_t* XS2 = (bf16_t*)take((size_t)NV * FD * sizeof(bf16_t));

  Ptr4 rows = {{ ei[0], ei[1], ei[2], ei[3] }};
  Ptr4 cols = {{ ei[0] + NE, ei[1] + NE, ei[2] + NE, ei[3] + NE }};

  // ---- prep ----
  p0_hist<<<dim3(NBLK, 4), 256, 0, stream>>>(rows, cols, blockCnt);
  scan_pass1<<<dim3(NSCH, 8), 256, 0, stream>>>(blockCnt, chunkSum);
  scan_pass2<<<1, 512, 0, stream>>>(chunkSum, bucketBase);
  scan_pass3<<<dim3(NSCH, 8), 256, 0, stream>>>(blockCnt, chunkSum, bucketBase);
  p1_scatter<<<dim3(NBLK, 4), 256, 0, stream>>>(rows, cols, blockCnt, pairD, srcb);
  p2_build<<<dim3(NBIN, 4), 256, 0, stream>>>(pairD, srcb, bucketBase,
                                              srcidx, rowptr, dinvD, dinvS);
  wprep<<<(8 * FD * FD + 255) / 256, 256, 0, stream>>>(Ws, Wtb);

  // ---- layers ----
  const dim3 GEMM_GRID((NV + 127) / 128, 2);   // 391 x 2 (share-X pairs)
  const dim3 PULL_GRID((NV + 3) / 4, 2);       // 12500 x 2
  const dim3 LIN_GRID((NV + 63) / 64, 2);
  const void* xd = x_drug;    // layer 1: fp32 inputs
  const void* xs = x_dis;
  bf16_t* nextd[2] = {XD1, XD2};
  bf16_t* nexts[2] = {XS1, XS2};
  for (int l = 0; l < 2; ++l) {
    const bf16_t* W0 = Wtb + (size_t)(l * 4 + 0) * FD * FD;
    const bf16_t* W1 = Wtb + (size_t)(l * 4 + 1) * FD * FD;
    const bf16_t* W2 = Wtb + (size_t)(l * 4 + 2) * FD * FD;
    const bf16_t* W3 = Wtb + (size_t)(l * 4 + 3) * FD * FD;
    const float* b0 = bs + (l * 4 + 0) * FD;
    const float* b1 = bs + (l * 4 + 1) * FD;
    const float* b2 = bs + (l * 4 + 2) * FD;
    const float* b3 = bs + (l * 4 + 3) * FD;

    // share-X pairs: drug X -> {r0:W0->hA, r2:W2->hD}; dis X -> {r1:W1->hC, r3:W3->hB}
    G2 gd, gs;
    gd.X = xd; gd.Wa = W0; gd.dSa = dinvS + 0 * NV; gd.Ha = hA;
               gd.Wb = W2; gd.dSb = dinvS + 2 * NV; gd.Hb = hD;
    gs.X = xs; gs.Wa = W1; gs.dSa = dinvS + 1 * NV; gs.Ha = hC;
               gs.Wb = W3; gs.dSb = dinvS + 3 * NV; gs.Hb = hB;
    if (l == 0) gemm_pairX<true><<<GEMM_GRID, 256, 0, stream>>>(gd, gs);
    else        gemm_pairX<false><<<GEMM_GRID, 256, 0, stream>>>(gd, gs);

    PullSide pd_;  // drug: A=dd(r0)->hA, B=sd(r3)->hB
    pd_.hA = hA; pd_.rpA = rowptr + 0 * (NV + 1); pd_.srcA = srcidx + (size_t)0 * NE;
    pd_.dDA = dinvD + 0 * NV;
    pd_.hB = hB; pd_.rpB = rowptr + 3 * (NV + 1); pd_.srcB = srcidx + (size_t)3 * NE;
    pd_.dDB = dinvD + 3 * NV;
    pd_.bA = b0; pd_.bB = b3; pd_.Y = nextd[l];
    PullSide ps_;  // dis: A=ss(r1)->hC, B=ds(r2)->hD
    ps_.hA = hC; ps_.rpA = rowptr + 1 * (NV + 1); ps_.srcA = srcidx + (size_t)1 * NE;
    ps_.dDA = dinvD + 1 * NV;
    ps_.hB = hD; ps_.rpB = rowptr + 2 * (NV + 1); ps_.srcB = srcidx + (size_t)2 * NE;
    ps_.dDB = dinvD + 2 * NV;
    ps_.bA = b1; ps_.bB = b2; ps_.Y = nexts[l];
    pull_dual<<<PULL_GRID, 256, 0, stream>>>(pd_, ps_);

    xd = nextd[l];
    xs = nexts[l];
  }

  linear64<<<LIN_GRID, 256, 0, stream>>>((const bf16_t*)xd, (const bf16_t*)xs,
                                         lw, lb, out);
}